// Round 1
// 2028.492 us; speedup vs baseline: 13.0188x; 13.0188x over previous
//
#include <hip/hip_runtime.h>
#include <hip/hip_bf16.h>

#define TOKENS 361
#define CDIM 512
#define NHEAD 8
#define DHEAD 64
#define MLPDIM 2048
#define BATCH 256
#define NTOK (BATCH * TOKENS) /* 92416 */
#define HTOK (NTOK / 2)       /* 46208 = 361*128 */
#define SPAN 37

typedef unsigned int uint32;

typedef __attribute__((ext_vector_type(8))) short bf16x8;
typedef __attribute__((ext_vector_type(4))) float f32x4;

__device__ __forceinline__ unsigned short f2bfu(float f) {
  union { float f; uint32 i; } c; c.f = f;
  uint32 i = c.i;
  uint32 r = (i + 0x7fffu + ((i >> 16) & 1u)) >> 16;
  return (unsigned short)r;
}
__device__ __forceinline__ float bfu2f(unsigned short u) {
  union { uint32 i; float f; } c; c.i = ((uint32)u) << 16; return c.f;
}
__device__ __forceinline__ float lo2f(uint32 u) {
  union { uint32 i; float f; } c; c.i = u << 16; return c.f;
}
__device__ __forceinline__ float hi2f(uint32 u) {
  union { uint32 i; float f; } c; c.i = u & 0xffff0000u; return c.f;
}

// ------------------------------------------------- transpose + fp32->bf16
// in fp32 [R, Cc] -> out bf16 [Cc, R]
__global__ __launch_bounds__(256) void transpose_conv(
    const float* __restrict__ in, unsigned short* __restrict__ out, int R, int Cc) {
  __shared__ float tile[32][33];
  int c0 = blockIdx.x * 32, r0 = blockIdx.y * 32;
  int tx = threadIdx.x & 31, ty = threadIdx.x >> 5;
#pragma unroll
  for (int i = 0; i < 32; i += 8)
    tile[ty + i][tx] = in[(size_t)(r0 + ty + i) * Cc + c0 + tx];
  __syncthreads();
#pragma unroll
  for (int i = 0; i < 32; i += 8)
    out[(size_t)(c0 + ty + i) * R + r0 + tx] = f2bfu(tile[tx][ty + i]);
}

// ------------------------------------------------- fused LayerNorm fp32 -> bf16
// one wave per token (512 elems, 8/lane)
__global__ __launch_bounds__(256) void ln_f32(
    const float* __restrict__ x, const float* __restrict__ sc,
    const float* __restrict__ bs, unsigned short* __restrict__ y) {
  int token = blockIdx.x * 4 + (threadIdx.x >> 6);
  int lane = threadIdx.x & 63;
  const float4* xp = (const float4*)(x + (size_t)token * CDIM + lane * 8);
  float4 f0 = xp[0], f1 = xp[1];
  float v[8] = {f0.x, f0.y, f0.z, f0.w, f1.x, f1.y, f1.z, f1.w};
  float sum = 0.f, sumsq = 0.f;
#pragma unroll
  for (int j = 0; j < 8; ++j) { sum += v[j]; sumsq += v[j] * v[j]; }
#pragma unroll
  for (int off = 1; off < 64; off <<= 1) {
    sum += __shfl_xor(sum, off);
    sumsq += __shfl_xor(sumsq, off);
  }
  float mu = sum * (1.f / 512.f);
  float var = sumsq * (1.f / 512.f) - mu * mu;
  float rs = rsqrtf(var + 1e-6f);
  const float4* sp = (const float4*)(sc + lane * 8);
  const float4* bp = (const float4*)(bs + lane * 8);
  float4 s0 = sp[0], s1 = sp[1], b0 = bp[0], b1 = bp[1];
  float sv[8] = {s0.x, s0.y, s0.z, s0.w, s1.x, s1.y, s1.z, s1.w};
  float bv[8] = {b0.x, b0.y, b0.z, b0.w, b1.x, b1.y, b1.z, b1.w};
  uint32 ov[4];
#pragma unroll
  for (int j = 0; j < 4; ++j) {
    float o0 = (v[2 * j] - mu) * rs * sv[2 * j] + bv[2 * j];
    float o1 = (v[2 * j + 1] - mu) * rs * sv[2 * j + 1] + bv[2 * j + 1];
    ov[j] = (uint32)f2bfu(o0) | ((uint32)f2bfu(o1) << 16);
  }
  uint4 outv = {ov[0], ov[1], ov[2], ov[3]};
  *(uint4*)(y + (size_t)token * CDIM + lane * 8) = outv;
}

// ------------------------------------------------- fused LayerNorm bf16 -> bf16
__global__ __launch_bounds__(256) void ln_bf16(
    const unsigned short* __restrict__ x, const float* __restrict__ sc,
    const float* __restrict__ bs, unsigned short* __restrict__ y) {
  int token = blockIdx.x * 4 + (threadIdx.x >> 6);
  int lane = threadIdx.x & 63;
  uint4 pk = *(const uint4*)(x + (size_t)token * CDIM + lane * 8);
  uint32 uu[4] = {pk.x, pk.y, pk.z, pk.w};
  float v[8];
#pragma unroll
  for (int j = 0; j < 4; ++j) { v[2 * j] = lo2f(uu[j]); v[2 * j + 1] = hi2f(uu[j]); }
  float sum = 0.f, sumsq = 0.f;
#pragma unroll
  for (int j = 0; j < 8; ++j) { sum += v[j]; sumsq += v[j] * v[j]; }
#pragma unroll
  for (int off = 1; off < 64; off <<= 1) {
    sum += __shfl_xor(sum, off);
    sumsq += __shfl_xor(sumsq, off);
  }
  float mu = sum * (1.f / 512.f);
  float var = sumsq * (1.f / 512.f) - mu * mu;
  float rs = rsqrtf(var + 1e-6f);
  const float4* sp = (const float4*)(sc + lane * 8);
  const float4* bp = (const float4*)(bs + lane * 8);
  float4 s0 = sp[0], s1 = sp[1], b0 = bp[0], b1 = bp[1];
  float sv[8] = {s0.x, s0.y, s0.z, s0.w, s1.x, s1.y, s1.z, s1.w};
  float bv[8] = {b0.x, b0.y, b0.z, b0.w, b1.x, b1.y, b1.z, b1.w};
  uint32 ov[4];
#pragma unroll
  for (int j = 0; j < 4; ++j) {
    float o0 = (v[2 * j] - mu) * rs * sv[2 * j] + bv[2 * j];
    float o1 = (v[2 * j + 1] - mu) * rs * sv[2 * j + 1] + bv[2 * j + 1];
    ov[j] = (uint32)f2bfu(o0) | ((uint32)f2bfu(o1) << 16);
  }
  uint4 outv = {ov[0], ov[1], ov[2], ov[3]};
  *(uint4*)(y + (size_t)token * CDIM + lane * 8) = outv;
}

__device__ __forceinline__ float gelu_tanh(float u) {
  float c2 = 0.7978845608028654f * (u + 0.044715f * u * u * u);
  float e = __expf(2.f * c2);
  float th = 1.f - 2.f / (e + 1.f);
  return 0.5f * u * (1.f + th);
}

// ------------------------------------------------- GEMM (B^T), bf16 MFMA
// C[M,N] = A[M,K] @ B + bias (+epilogue). BT is [N,K] bf16. bias fp32.
// EPI 0: store bf16. EPI 1: gelu, store bf16.
// EPI 2: += resf (fp32), store bf16. EPI 3: += resb (bf16), store fp32.
#define LSTR 40
template <int EPI>
__global__ __launch_bounds__(256) void gemm_bt(
    const unsigned short* __restrict__ A, const unsigned short* __restrict__ BT,
    const float* __restrict__ bias, const float* __restrict__ resf,
    const unsigned short* __restrict__ resb, void* __restrict__ Cc,
    int M, int N, int K) {
  __shared__ unsigned short As[128 * LSTR];
  __shared__ unsigned short Bs[128 * LSTR];
  int tid = threadIdx.x;
  int wave = tid >> 6, lane = tid & 63;
  int quad = lane >> 4, l16 = lane & 15;
  int m0 = blockIdx.x * 128, n0 = blockIdx.y * 128;
  int wm = (wave >> 1) * 64, wn = (wave & 1) * 64;

  f32x4 acc[4][4];
#pragma unroll
  for (int i = 0; i < 4; ++i)
#pragma unroll
    for (int j = 0; j < 4; ++j) acc[i][j] = (f32x4){0.f, 0.f, 0.f, 0.f};

  int rA = tid >> 2;
  int kc = (tid & 3) * 8;
  const unsigned short* Ap = A + (size_t)(m0 + rA) * K + kc;
  const unsigned short* Ap2 = A + (size_t)(m0 + rA + 64) * K + kc;
  const unsigned short* Bp = BT + (size_t)(n0 + rA) * K + kc;
  const unsigned short* Bp2 = BT + (size_t)(n0 + rA + 64) * K + kc;
  unsigned short* Asw = &As[rA * LSTR + kc];
  unsigned short* Bsw = &Bs[rA * LSTR + kc];

  for (int k0 = 0; k0 < K; k0 += 32) {
    uint4 a0 = *(const uint4*)(Ap + k0);
    uint4 a1 = *(const uint4*)(Ap2 + k0);
    uint4 b0 = *(const uint4*)(Bp + k0);
    uint4 b1 = *(const uint4*)(Bp2 + k0);
    __syncthreads();
    *(uint4*)Asw = a0;
    *(uint4*)(Asw + 64 * LSTR) = a1;
    *(uint4*)Bsw = b0;
    *(uint4*)(Bsw + 64 * LSTR) = b1;
    __syncthreads();
    bf16x8 af[4], bfr[4];
#pragma unroll
    for (int mi = 0; mi < 4; ++mi)
      af[mi] = *(const bf16x8*)&As[(wm + mi * 16 + l16) * LSTR + quad * 8];
#pragma unroll
    for (int ni = 0; ni < 4; ++ni)
      bfr[ni] = *(const bf16x8*)&Bs[(wn + ni * 16 + l16) * LSTR + quad * 8];
#pragma unroll
    for (int mi = 0; mi < 4; ++mi)
#pragma unroll
      for (int ni = 0; ni < 4; ++ni)
        acc[mi][ni] = __builtin_amdgcn_mfma_f32_16x16x32_bf16(af[mi], bfr[ni], acc[mi][ni], 0, 0, 0);
  }

  unsigned short* o16 = (unsigned short*)Cc;
  float* o32 = (float*)Cc;
#pragma unroll
  for (int ni = 0; ni < 4; ++ni) {
    int gc = n0 + wn + ni * 16 + l16;
    float bz = bias[gc];
#pragma unroll
    for (int mi = 0; mi < 4; ++mi) {
#pragma unroll
      for (int r = 0; r < 4; ++r) {
        int gr = m0 + wm + mi * 16 + quad * 4 + r;
        float val = acc[mi][ni][r] + bz;
        if (EPI == 1) val = gelu_tanh(val);
        if (EPI == 2) val += resf[(size_t)gr * N + gc];
        if (EPI == 3) val += bfu2f(resb[(size_t)gr * N + gc]);
        if (EPI == 3) o32[(size_t)gr * N + gc] = val;
        else o16[(size_t)gr * N + gc] = f2bfu(val);
      }
    }
  }
}

// ------------------------------------------------- MFMA attention
// one block (4 waves) per (b,h). K [368x72] and V^T [64x392] staged in LDS,
// S = Q K^T via mfma (23 n-tiles register-resident), wave-local softmax,
// P (normalized, bf16) -> LDS, ctx = P V via mfma.
#define SROW 72   /* Ks stride, shorts; word-stride 36 ≡ 4 mod 32 -> 2-way banks */
#define PSTR 392  /* VT/Ps stride, shorts; word-stride 196 ≡ 4 mod 32 */
__global__ __launch_bounds__(256, 1) void attn_mfma(
    const unsigned short* __restrict__ q, const unsigned short* __restrict__ k,
    const unsigned short* __restrict__ v, const float* __restrict__ relb,
    unsigned short* __restrict__ ctx) {
  __shared__ unsigned short Ks[368 * SROW];  // 52992 B
  __shared__ unsigned short VT[64 * PSTR];   // 50176 B
  __shared__ unsigned short Ps[64 * PSTR];   // 50176 B
  __shared__ float biasF[1369];              //  5476 B  -> 158820 B total
  int b = blockIdx.x >> 3, h = blockIdx.x & 7;
  int tid = threadIdx.x;
  int wave = tid >> 6, lane = tid & 63;
  int quad = lane >> 4, l16 = lane & 15;
  size_t base = ((size_t)b * TOKENS) * CDIM + h * DHEAD;

  // stage K rows (16B chunks, coalesced)
  for (int vv = tid; vv < TOKENS * 8; vv += 256) {
    int r = vv >> 3, c = (vv & 7) * 8;
    *(uint4*)&Ks[r * SROW + c] = *(const uint4*)(k + base + (size_t)r * CDIM + c);
  }
  if (tid < 56) {  // zero pad rows 361..367
    int r = 361 + (tid >> 3), c = (tid & 7) * 8;
    *(uint4*)&Ks[r * SROW + c] = (uint4){0u, 0u, 0u, 0u};
  }
  // stage V transposed: VT[d][s] (scalar scatter; one-time cost per block)
  for (int vv = tid; vv < TOKENS * 8; vv += 256) {
    int s = vv >> 3, c = (vv & 7) * 8;
    uint4 pk = *(const uint4*)(v + base + (size_t)s * CDIM + c);
    unsigned short* dst = &VT[c * PSTR + s];
    uint32 w0 = pk.x, w1 = pk.y, w2 = pk.z, w3 = pk.w;
    dst[0]        = (unsigned short)w0;  dst[PSTR]     = (unsigned short)(w0 >> 16);
    dst[2 * PSTR] = (unsigned short)w1;  dst[3 * PSTR] = (unsigned short)(w1 >> 16);
    dst[4 * PSTR] = (unsigned short)w2;  dst[5 * PSTR] = (unsigned short)(w2 >> 16);
    dst[6 * PSTR] = (unsigned short)w3;  dst[7 * PSTR] = (unsigned short)(w3 >> 16);
  }
  // zero pad VT cols 361..383
  for (int vv = tid; vv < 64 * 23; vv += 256) {
    int s = 361 + (vv >> 6), d = vv & 63;
    VT[d * PSTR + s] = 0;
  }
  for (int i = tid; i < 1369; i += 256) biasF[i] = relb[h * 1369 + i];
  // zero own-wave Ps pad cols 368..383 (persist across m-tiles)
  for (int i = lane; i < 256; i += 64) {
    int rr = i >> 4, cc = i & 15;
    Ps[(wave * 16 + rr) * PSTR + 368 + cc] = 0;
  }
  __syncthreads();

  for (int t0 = 0; t0 < TOKENS; t0 += 64) {
    int rowb = t0 + wave * 16;
    // Q A-fragments (row = l16, k-slice = quad*8, two K=32 halves)
    const unsigned short* qrow = q + base + (size_t)(rowb + l16) * CDIM + quad * 8;
    bf16x8 aq0 = *(const bf16x8*)(qrow);
    bf16x8 aq1 = *(const bf16x8*)(qrow + 32);
    int tb[4];
#pragma unroll
    for (int r = 0; r < 4; ++r) {
      int t = rowb + quad * 4 + r;
      if (t > 360) t = 360;  // clamp garbage rows: keeps bias index in range
      int rt = t / 19, ct = t - rt * 19;
      tb[r] = rt * SPAN + ct + (18 * SPAN + 18);
    }
    // ---- S = Q K^T, 23 column tiles, register resident
    f32x4 sc[23];
#pragma unroll
    for (int n = 0; n < 23; ++n) {
      const unsigned short* kr = &Ks[(n * 16 + l16) * SROW + quad * 8];
      bf16x8 b0 = *(const bf16x8*)kr;
      bf16x8 b1 = *(const bf16x8*)(kr + 32);
      f32x4 a = {0.f, 0.f, 0.f, 0.f};
      a = __builtin_amdgcn_mfma_f32_16x16x32_bf16(aq0, b0, a, 0, 0, 0);
      a = __builtin_amdgcn_mfma_f32_16x16x32_bf16(aq1, b1, a, 0, 0, 0);
      sc[n] = a;
    }
    // ---- scale + rel-bias + row max
    float mx[4] = {-1e30f, -1e30f, -1e30f, -1e30f};
#pragma unroll
    for (int n = 0; n < 23; ++n) {
      int s = n * 16 + l16;
      int sv = s > 360 ? 360 : s;
      int rs = sv / 19, cs = sv - rs * 19;
      int sb = rs * SPAN + cs;
#pragma unroll
      for (int r = 0; r < 4; ++r) {
        float val = sc[n][r] * 0.125f + biasF[tb[r] - sb];
        if (s > 360) val = -1e30f;
        sc[n][r] = val;
        mx[r] = fmaxf(mx[r], val);
      }
    }
#pragma unroll
    for (int off = 1; off < 16; off <<= 1)
#pragma unroll
      for (int r = 0; r < 4; ++r) mx[r] = fmaxf(mx[r], __shfl_xor(mx[r], off));
    // ---- exp + row sum
    float sm[4] = {0.f, 0.f, 0.f, 0.f};
#pragma unroll
    for (int n = 0; n < 23; ++n)
#pragma unroll
      for (int r = 0; r < 4; ++r) {
        float p = __expf(sc[n][r] - mx[r]);
        sc[n][r] = p;
        sm[r] += p;
      }
#pragma unroll
    for (int off = 1; off < 16; off <<= 1)
#pragma unroll
      for (int r = 0; r < 4; ++r) sm[r] += __shfl_xor(sm[r], off);
    float inv[4];
#pragma unroll
    for (int r = 0; r < 4; ++r) inv[r] = 1.f / sm[r];
    // ---- write normalized P (bf16) to own-wave rows
#pragma unroll
    for (int n = 0; n < 23; ++n)
#pragma unroll
      for (int r = 0; r < 4; ++r)
        Ps[(wave * 16 + quad * 4 + r) * PSTR + n * 16 + l16] = f2bfu(sc[n][r] * inv[r]);
    // ---- ctx = P @ V  (A = P rows, B = V^T rows)
    f32x4 pacc[4];
#pragma unroll
    for (int ni = 0; ni < 4; ++ni) pacc[ni] = (f32x4){0.f, 0.f, 0.f, 0.f};
#pragma unroll
    for (int kk = 0; kk < 12; ++kk) {
      bf16x8 pa = *(const bf16x8*)&Ps[(wave * 16 + l16) * PSTR + kk * 32 + quad * 8];
#pragma unroll
      for (int ni = 0; ni < 4; ++ni) {
        bf16x8 vb = *(const bf16x8*)&VT[(ni * 16 + l16) * PSTR + kk * 32 + quad * 8];
        pacc[ni] = __builtin_amdgcn_mfma_f32_16x16x32_bf16(pa, vb, pacc[ni], 0, 0, 0);
      }
    }
#pragma unroll
    for (int ni = 0; ni < 4; ++ni)
#pragma unroll
      for (int r = 0; r < 4; ++r) {
        int t = rowb + quad * 4 + r;
        if (t < TOKENS)
          ctx[base + (size_t)t * CDIM + ni * 16 + l16] = f2bfu(pacc[ni][r]);
      }
  }
}

// ------------------------------------------------- launch
extern "C" void kernel_launch(void* const* d_in, const int* in_sizes, int n_in,
                              void* d_out, int out_size, void* d_ws, size_t ws_size,
                              hipStream_t stream) {
  const float* x     = (const float*)d_in[0];
  const float* ln1_s = (const float*)d_in[1];
  const float* ln1_b = (const float*)d_in[2];
  const float* Wq    = (const float*)d_in[3];
  const float* bq    = (const float*)d_in[4];
  const float* Wk    = (const float*)d_in[5];
  const float* bk    = (const float*)d_in[6];
  const float* Wv    = (const float*)d_in[7];
  const float* bv    = (const float*)d_in[8];
  const float* Wo    = (const float*)d_in[9];
  const float* bo    = (const float*)d_in[10];
  const float* relb  = (const float*)d_in[11];
  const float* ln2_s = (const float*)d_in[12];
  const float* ln2_b = (const float*)d_in[13];
  const float* W1    = (const float*)d_in[14];
  const float* b1    = (const float*)d_in[15];
  const float* W2    = (const float*)d_in[16];
  const float* b2    = (const float*)d_in[17];
  float* out = (float*)d_out;

  // ws layout (~385 MB): bf16 weights 6.3 MB | y 94.6 MB | x1b 94.6 MB |
  // q/k/v/ctx half-batch 4x47.3 MB (overlaid by MLP hidden)
  char* ws = (char*)d_ws;
  unsigned short* WqT = (unsigned short*)ws;
  unsigned short* WkT = WqT + 512 * 512;
  unsigned short* WvT = WkT + 512 * 512;
  unsigned short* WoT = WvT + 512 * 512;
  unsigned short* W1T = WoT + 512 * 512;
  unsigned short* W2T = W1T + 512 * 2048;
  unsigned short* yb  = W2T + 2048 * 512;          // NTOK*512 bf16
  unsigned short* x1b = yb + (size_t)NTOK * CDIM;  // NTOK*512 bf16
  unsigned short* qb  = x1b + (size_t)NTOK * CDIM;
  const size_t HS = (size_t)HTOK * CDIM;
  unsigned short* kb   = qb + HS;
  unsigned short* vb   = kb + HS;
  unsigned short* ctxb = vb + HS;
  unsigned short* hdn  = qb;  // HTOK*2048 bf16, overlays q/k/v/ctx

  dim3 blk(256);
  transpose_conv<<<dim3(16, 16), blk, 0, stream>>>(Wq, WqT, 512, 512);
  transpose_conv<<<dim3(16, 16), blk, 0, stream>>>(Wk, WkT, 512, 512);
  transpose_conv<<<dim3(16, 16), blk, 0, stream>>>(Wv, WvT, 512, 512);
  transpose_conv<<<dim3(16, 16), blk, 0, stream>>>(Wo, WoT, 512, 512);
  transpose_conv<<<dim3(64, 16), blk, 0, stream>>>(W1, W1T, 512, 2048);
  transpose_conv<<<dim3(16, 64), blk, 0, stream>>>(W2, W2T, 2048, 512);

  ln_f32<<<NTOK / 4, blk, 0, stream>>>(x, ln1_s, ln1_b, yb);

  for (int c = 0; c < 2; ++c) {
    size_t off = (size_t)c * HTOK;
    const unsigned short* yc = yb + off * CDIM;
    gemm_bt<0><<<dim3(361, 4), blk, 0, stream>>>(yc, WqT, bq, nullptr, nullptr, qb, HTOK, 512, 512);
    gemm_bt<0><<<dim3(361, 4), blk, 0, stream>>>(yc, WkT, bk, nullptr, nullptr, kb, HTOK, 512, 512);
    gemm_bt<0><<<dim3(361, 4), blk, 0, stream>>>(yc, WvT, bv, nullptr, nullptr, vb, HTOK, 512, 512);
    attn_mfma<<<dim3((BATCH / 2) * NHEAD), blk, 0, stream>>>(qb, kb, vb, relb, ctxb);
    gemm_bt<2><<<dim3(361, 4), blk, 0, stream>>>(ctxb, WoT, bo, x + off * CDIM, nullptr,
                                                 x1b + off * CDIM, HTOK, 512, 512);
  }

  ln_bf16<<<NTOK / 4, blk, 0, stream>>>(x1b, ln2_s, ln2_b, yb);

  for (int c = 0; c < 2; ++c) {
    size_t off = (size_t)c * HTOK;
    gemm_bt<1><<<dim3(361, 16), blk, 0, stream>>>(yb + off * CDIM, W1T, b1, nullptr, nullptr,
                                                  hdn, HTOK, 2048, 512);
    gemm_bt<3><<<dim3(361, 4), blk, 0, stream>>>(hdn, W2T, b2, nullptr, x1b + off * CDIM,
                                                 out + off * CDIM, HTOK, 512, 2048);
  }
}

// Round 2
// 1893.087 us; speedup vs baseline: 13.9500x; 1.0715x over previous
//
#include <hip/hip_runtime.h>
#include <hip/hip_bf16.h>

#define TOKENS 361
#define CDIM 512
#define NHEAD 8
#define DHEAD 64
#define MLPDIM 2048
#define BATCH 256
#define NTOK (BATCH * TOKENS) /* 92416 */
#define HTOK (NTOK / 2)       /* 46208 = 361*128 */
#define SPAN 37
#define QKVSTR 1536

typedef unsigned int uint32;

typedef __attribute__((ext_vector_type(8))) short bf16x8;
typedef __attribute__((ext_vector_type(4))) float f32x4;

__device__ __forceinline__ unsigned short f2bfu(float f) {
  union { float f; uint32 i; } c; c.f = f;
  uint32 i = c.i;
  uint32 r = (i + 0x7fffu + ((i >> 16) & 1u)) >> 16;
  return (unsigned short)r;
}
__device__ __forceinline__ float bfu2f(unsigned short u) {
  union { uint32 i; float f; } c; c.i = ((uint32)u) << 16; return c.f;
}
__device__ __forceinline__ float lo2f(uint32 u) {
  union { uint32 i; float f; } c; c.i = u << 16; return c.f;
}
__device__ __forceinline__ float hi2f(uint32 u) {
  union { uint32 i; float f; } c; c.i = u & 0xffff0000u; return c.f;
}

// async global->LDS, 16B per lane. LDS dest must be wave-uniform base (+lane*16).
__device__ __forceinline__ void gload16(const void* g, void* l) {
  __builtin_amdgcn_global_load_lds((const __attribute__((address_space(1))) void*)g,
                                   (__attribute__((address_space(3))) void*)l, 16, 0, 0);
}

// ------------------------------------------------- transpose + fp32->bf16
// in fp32 [R, Cc] -> out bf16 [Cc, R]
__global__ __launch_bounds__(256) void transpose_conv(
    const float* __restrict__ in, unsigned short* __restrict__ out, int R, int Cc) {
  __shared__ float tile[32][33];
  int c0 = blockIdx.x * 32, r0 = blockIdx.y * 32;
  int tx = threadIdx.x & 31, ty = threadIdx.x >> 5;
#pragma unroll
  for (int i = 0; i < 32; i += 8)
    tile[ty + i][tx] = in[(size_t)(r0 + ty + i) * Cc + c0 + tx];
  __syncthreads();
#pragma unroll
  for (int i = 0; i < 32; i += 8)
    out[(size_t)(c0 + ty + i) * R + r0 + tx] = f2bfu(tile[tx][ty + i]);
}

// ------------------------------------------------- concat q/k/v biases
__global__ __launch_bounds__(256) void concat_bias(
    const float* __restrict__ a, const float* __restrict__ b,
    const float* __restrict__ c, float* __restrict__ o) {
  int i = blockIdx.x * 256 + threadIdx.x;
  o[i] = i < 512 ? a[i] : (i < 1024 ? b[i - 512] : c[i - 1024]);
}

// ------------------------------------------------- fused LayerNorm fp32 -> bf16
__global__ __launch_bounds__(256) void ln_f32(
    const float* __restrict__ x, const float* __restrict__ sc,
    const float* __restrict__ bs, unsigned short* __restrict__ y) {
  int token = blockIdx.x * 4 + (threadIdx.x >> 6);
  int lane = threadIdx.x & 63;
  const float4* xp = (const float4*)(x + (size_t)token * CDIM + lane * 8);
  float4 f0 = xp[0], f1 = xp[1];
  float v[8] = {f0.x, f0.y, f0.z, f0.w, f1.x, f1.y, f1.z, f1.w};
  float sum = 0.f, sumsq = 0.f;
#pragma unroll
  for (int j = 0; j < 8; ++j) { sum += v[j]; sumsq += v[j] * v[j]; }
#pragma unroll
  for (int off = 1; off < 64; off <<= 1) {
    sum += __shfl_xor(sum, off);
    sumsq += __shfl_xor(sumsq, off);
  }
  float mu = sum * (1.f / 512.f);
  float var = sumsq * (1.f / 512.f) - mu * mu;
  float rs = rsqrtf(var + 1e-6f);
  const float4* sp = (const float4*)(sc + lane * 8);
  const float4* bp = (const float4*)(bs + lane * 8);
  float4 s0 = sp[0], s1 = sp[1], b0 = bp[0], b1 = bp[1];
  float sv[8] = {s0.x, s0.y, s0.z, s0.w, s1.x, s1.y, s1.z, s1.w};
  float bv[8] = {b0.x, b0.y, b0.z, b0.w, b1.x, b1.y, b1.z, b1.w};
  uint32 ov[4];
#pragma unroll
  for (int j = 0; j < 4; ++j) {
    float o0 = (v[2 * j] - mu) * rs * sv[2 * j] + bv[2 * j];
    float o1 = (v[2 * j + 1] - mu) * rs * sv[2 * j + 1] + bv[2 * j + 1];
    ov[j] = (uint32)f2bfu(o0) | ((uint32)f2bfu(o1) << 16);
  }
  uint4 outv = {ov[0], ov[1], ov[2], ov[3]};
  *(uint4*)(y + (size_t)token * CDIM + lane * 8) = outv;
}

// ------------------------------------------------- fused LayerNorm bf16 -> bf16
__global__ __launch_bounds__(256) void ln_bf16(
    const unsigned short* __restrict__ x, const float* __restrict__ sc,
    const float* __restrict__ bs, unsigned short* __restrict__ y) {
  int token = blockIdx.x * 4 + (threadIdx.x >> 6);
  int lane = threadIdx.x & 63;
  uint4 pk = *(const uint4*)(x + (size_t)token * CDIM + lane * 8);
  uint32 uu[4] = {pk.x, pk.y, pk.z, pk.w};
  float v[8];
#pragma unroll
  for (int j = 0; j < 4; ++j) { v[2 * j] = lo2f(uu[j]); v[2 * j + 1] = hi2f(uu[j]); }
  float sum = 0.f, sumsq = 0.f;
#pragma unroll
  for (int j = 0; j < 8; ++j) { sum += v[j]; sumsq += v[j] * v[j]; }
#pragma unroll
  for (int off = 1; off < 64; off <<= 1) {
    sum += __shfl_xor(sum, off);
    sumsq += __shfl_xor(sumsq, off);
  }
  float mu = sum * (1.f / 512.f);
  float var = sumsq * (1.f / 512.f) - mu * mu;
  float rs = rsqrtf(var + 1e-6f);
  const float4* sp = (const float4*)(sc + lane * 8);
  const float4* bp = (const float4*)(bs + lane * 8);
  float4 s0 = sp[0], s1 = sp[1], b0 = bp[0], b1 = bp[1];
  float sv[8] = {s0.x, s0.y, s0.z, s0.w, s1.x, s1.y, s1.z, s1.w};
  float bv[8] = {b0.x, b0.y, b0.z, b0.w, b1.x, b1.y, b1.z, b1.w};
  uint32 ov[4];
#pragma unroll
  for (int j = 0; j < 4; ++j) {
    float o0 = (v[2 * j] - mu) * rs * sv[2 * j] + bv[2 * j];
    float o1 = (v[2 * j + 1] - mu) * rs * sv[2 * j + 1] + bv[2 * j + 1];
    ov[j] = (uint32)f2bfu(o0) | ((uint32)f2bfu(o1) << 16);
  }
  uint4 outv = {ov[0], ov[1], ov[2], ov[3]};
  *(uint4*)(y + (size_t)token * CDIM + lane * 8) = outv;
}

__device__ __forceinline__ float gelu_tanh(float u) {
  float c2 = 0.7978845608028654f * (u + 0.044715f * u * u * u);
  float e = __expf(2.f * c2);
  float th = 1.f - 2.f / (e + 1.f);
  return 0.5f * u * (1.f + th);
}

// ------------------------------------------------- GEMM (B^T), bf16 MFMA
// C[M,N] = A[M,K] @ B + bias (+epilogue). BT is [N,K] bf16. bias fp32.
// EPI 0: store bf16. EPI 1: gelu, store bf16.
// EPI 2: += resf (fp32), store bf16. EPI 3: += resb (bf16), store fp32.
// 1-D grid, N-fastest logical order, bijective XCD-chunked swizzle (m204).
// Staging via global_load_lds(16B), linear LDS [128][32] per matrix.
template <int EPI>
__global__ __launch_bounds__(256) void gemm_bt(
    const unsigned short* __restrict__ A, const unsigned short* __restrict__ BT,
    const float* __restrict__ bias, const float* __restrict__ resf,
    const unsigned short* __restrict__ resb, void* __restrict__ Cc,
    int M, int N, int K, int nbx) {
  __shared__ unsigned short As[128 * 32];  // 8 KB
  __shared__ unsigned short Bs[128 * 32];  // 8 KB
  int tid = threadIdx.x;
  int wave = tid >> 6, lane = tid & 63;
  int quad = lane >> 4, l16 = lane & 15;

  // XCD-chunked bijective remap: XCD k gets a contiguous logical chunk.
  int nwg = gridDim.x, bid = blockIdx.x;
  int qq = nwg >> 3, rr = nwg & 7;
  int xcd = bid & 7, loc = bid >> 3;
  int L = (xcd < rr ? xcd * (qq + 1) : rr * (qq + 1) + (xcd - rr) * qq) + loc;
  int m0 = (L / nbx) * 128, n0 = (L % nbx) * 128;
  int wm = (wave >> 1) * 64, wn = (wave & 1) * 64;

  f32x4 acc[4][4];
#pragma unroll
  for (int i = 0; i < 4; ++i)
#pragma unroll
    for (int j = 0; j < 4; ++j) acc[i][j] = (f32x4){0.f, 0.f, 0.f, 0.f};

  // staging: row = tid>>2 (64 rows/issue), 16B chunk = tid&3
  const unsigned short* gA = A + (size_t)(m0 + (tid >> 2)) * K + (tid & 3) * 8;
  const unsigned short* gA2 = gA + (size_t)64 * K;
  const unsigned short* gB = BT + (size_t)(n0 + (tid >> 2)) * K + (tid & 3) * 8;
  const unsigned short* gB2 = gB + (size_t)64 * K;
  unsigned short* lA0 = As + wave * 512;         // rows 0-63
  unsigned short* lA1 = As + 2048 + wave * 512;  // rows 64-127
  unsigned short* lB0 = Bs + wave * 512;
  unsigned short* lB1 = Bs + 2048 + wave * 512;

  for (int k0 = 0; k0 < K; k0 += 32) {
    __syncthreads();  // all waves done reading previous tile
    gload16(gA + k0, lA0);
    gload16(gA2 + k0, lA1);
    gload16(gB + k0, lB0);
    gload16(gB2 + k0, lB1);
    __syncthreads();  // vmcnt(0) drained by barrier -> tile ready
    bf16x8 af[4], bfr[4];
#pragma unroll
    for (int mi = 0; mi < 4; ++mi)
      af[mi] = *(const bf16x8*)&As[(wm + mi * 16 + l16) * 32 + quad * 8];
#pragma unroll
    for (int ni = 0; ni < 4; ++ni)
      bfr[ni] = *(const bf16x8*)&Bs[(wn + ni * 16 + l16) * 32 + quad * 8];
#pragma unroll
    for (int mi = 0; mi < 4; ++mi)
#pragma unroll
      for (int ni = 0; ni < 4; ++ni)
        acc[mi][ni] = __builtin_amdgcn_mfma_f32_16x16x32_bf16(af[mi], bfr[ni], acc[mi][ni], 0, 0, 0);
  }

  unsigned short* o16 = (unsigned short*)Cc;
  float* o32 = (float*)Cc;
#pragma unroll
  for (int ni = 0; ni < 4; ++ni) {
    int gc = n0 + wn + ni * 16 + l16;
    float bz = bias[gc];
#pragma unroll
    for (int mi = 0; mi < 4; ++mi) {
#pragma unroll
      for (int r = 0; r < 4; ++r) {
        int gr = m0 + wm + mi * 16 + quad * 4 + r;
        float val = acc[mi][ni][r] + bz;
        if (EPI == 1) val = gelu_tanh(val);
        if (EPI == 2) val += resf[(size_t)gr * N + gc];
        if (EPI == 3) val += bfu2f(resb[(size_t)gr * N + gc]);
        if (EPI == 3) o32[(size_t)gr * N + gc] = val;
        else o16[(size_t)gr * N + gc] = f2bfu(val);
      }
    }
  }
}

// ------------------------------------------------- MFMA attention
// one block (4 waves) per (b,h). qkv packed [HTOK][1536] (q|k|v per row).
#define SROW 72   /* Ks stride, shorts */
#define PSTR 392  /* VT/Ps stride, shorts */
__global__ __launch_bounds__(256, 1) void attn_mfma(
    const unsigned short* __restrict__ qkv, const float* __restrict__ relb,
    unsigned short* __restrict__ ctx) {
  __shared__ unsigned short Ks[368 * SROW];  // 52992 B
  __shared__ unsigned short VT[64 * PSTR];   // 50176 B
  __shared__ unsigned short Ps[64 * PSTR];   // 50176 B
  __shared__ float biasF[1369];
  int b = blockIdx.x >> 3, h = blockIdx.x & 7;
  int tid = threadIdx.x;
  int wave = tid >> 6, lane = tid & 63;
  int quad = lane >> 4, l16 = lane & 15;
  size_t baseq = ((size_t)b * TOKENS) * QKVSTR + h * DHEAD;
  size_t basec = ((size_t)b * TOKENS) * CDIM + h * DHEAD;
  const unsigned short* kp = qkv + baseq + 512;
  const unsigned short* vp = qkv + baseq + 1024;

  // stage K rows (16B chunks, coalesced)
  for (int vv = tid; vv < TOKENS * 8; vv += 256) {
    int r = vv >> 3, c = (vv & 7) * 8;
    *(uint4*)&Ks[r * SROW + c] = *(const uint4*)(kp + (size_t)r * QKVSTR + c);
  }
  if (tid < 56) {  // zero pad rows 361..367
    int r = 361 + (tid >> 3), c = (tid & 7) * 8;
    *(uint4*)&Ks[r * SROW + c] = (uint4){0u, 0u, 0u, 0u};
  }
  // stage V transposed: VT[d][s]
  for (int vv = tid; vv < TOKENS * 8; vv += 256) {
    int s = vv >> 3, c = (vv & 7) * 8;
    uint4 pk = *(const uint4*)(vp + (size_t)s * QKVSTR + c);
    unsigned short* dst = &VT[c * PSTR + s];
    uint32 w0 = pk.x, w1 = pk.y, w2 = pk.z, w3 = pk.w;
    dst[0]        = (unsigned short)w0;  dst[PSTR]     = (unsigned short)(w0 >> 16);
    dst[2 * PSTR] = (unsigned short)w1;  dst[3 * PSTR] = (unsigned short)(w1 >> 16);
    dst[4 * PSTR] = (unsigned short)w2;  dst[5 * PSTR] = (unsigned short)(w2 >> 16);
    dst[6 * PSTR] = (unsigned short)w3;  dst[7 * PSTR] = (unsigned short)(w3 >> 16);
  }
  for (int vv = tid; vv < 64 * 23; vv += 256) {
    int s = 361 + (vv >> 6), d = vv & 63;
    VT[d * PSTR + s] = 0;
  }
  for (int i = tid; i < 1369; i += 256) biasF[i] = relb[h * 1369 + i];
  for (int i = lane; i < 256; i += 64) {
    int rrp = i >> 4, cc = i & 15;
    Ps[(wave * 16 + rrp) * PSTR + 368 + cc] = 0;
  }
  __syncthreads();

  for (int t0 = 0; t0 < TOKENS; t0 += 64) {
    int rowb = t0 + wave * 16;
    const unsigned short* qrow = qkv + baseq + (size_t)(rowb + l16) * QKVSTR + quad * 8;
    bf16x8 aq0 = *(const bf16x8*)(qrow);
    bf16x8 aq1 = *(const bf16x8*)(qrow + 32);
    int tb[4];
#pragma unroll
    for (int r = 0; r < 4; ++r) {
      int t = rowb + quad * 4 + r;
      if (t > 360) t = 360;
      int rt = t / 19, ct = t - rt * 19;
      tb[r] = rt * SPAN + ct + (18 * SPAN + 18);
    }
    // ---- S = Q K^T
    f32x4 sc[23];
#pragma unroll
    for (int n = 0; n < 23; ++n) {
      const unsigned short* kr = &Ks[(n * 16 + l16) * SROW + quad * 8];
      bf16x8 b0 = *(const bf16x8*)kr;
      bf16x8 b1 = *(const bf16x8*)(kr + 32);
      f32x4 a = {0.f, 0.f, 0.f, 0.f};
      a = __builtin_amdgcn_mfma_f32_16x16x32_bf16(aq0, b0, a, 0, 0, 0);
      a = __builtin_amdgcn_mfma_f32_16x16x32_bf16(aq1, b1, a, 0, 0, 0);
      sc[n] = a;
    }
    // ---- scale + rel-bias + row max
    float mx[4] = {-1e30f, -1e30f, -1e30f, -1e30f};
#pragma unroll
    for (int n = 0; n < 23; ++n) {
      int s = n * 16 + l16;
      int sv = s > 360 ? 360 : s;
      int rs = sv / 19, cs = sv - rs * 19;
      int sb = rs * SPAN + cs;
#pragma unroll
      for (int r = 0; r < 4; ++r) {
        float val = sc[n][r] * 0.125f + biasF[tb[r] - sb];
        if (s > 360) val = -1e30f;
        sc[n][r] = val;
        mx[r] = fmaxf(mx[r], val);
      }
    }
#pragma unroll
    for (int off = 1; off < 16; off <<= 1)
#pragma unroll
      for (int r = 0; r < 4; ++r) mx[r] = fmaxf(mx[r], __shfl_xor(mx[r], off));
    // ---- exp + row sum
    float sm[4] = {0.f, 0.f, 0.f, 0.f};
#pragma unroll
    for (int n = 0; n < 23; ++n)
#pragma unroll
      for (int r = 0; r < 4; ++r) {
        float p = __expf(sc[n][r] - mx[r]);
        sc[n][r] = p;
        sm[r] += p;
      }
#pragma unroll
    for (int off = 1; off < 16; off <<= 1)
#pragma unroll
      for (int r = 0; r < 4; ++r) sm[r] += __shfl_xor(sm[r], off);
    float inv[4];
#pragma unroll
    for (int r = 0; r < 4; ++r) inv[r] = 1.f / sm[r];
#pragma unroll
    for (int n = 0; n < 23; ++n)
#pragma unroll
      for (int r = 0; r < 4; ++r)
        Ps[(wave * 16 + quad * 4 + r) * PSTR + n * 16 + l16] = f2bfu(sc[n][r] * inv[r]);
    // ---- ctx = P @ V
    f32x4 pacc[4];
#pragma unroll
    for (int ni = 0; ni < 4; ++ni) pacc[ni] = (f32x4){0.f, 0.f, 0.f, 0.f};
#pragma unroll
    for (int kk = 0; kk < 12; ++kk) {
      bf16x8 pa = *(const bf16x8*)&Ps[(wave * 16 + l16) * PSTR + kk * 32 + quad * 8];
#pragma unroll
      for (int ni = 0; ni < 4; ++ni) {
        bf16x8 vb = *(const bf16x8*)&VT[(ni * 16 + l16) * PSTR + kk * 32 + quad * 8];
        pacc[ni] = __builtin_amdgcn_mfma_f32_16x16x32_bf16(pa, vb, pacc[ni], 0, 0, 0);
      }
    }
#pragma unroll
    for (int ni = 0; ni < 4; ++ni)
#pragma unroll
      for (int r = 0; r < 4; ++r) {
        int t = rowb + quad * 4 + r;
        if (t < TOKENS)
          ctx[basec + (size_t)t * CDIM + ni * 16 + l16] = f2bfu(pacc[ni][r]);
      }
  }
}

// ------------------------------------------------- launch
extern "C" void kernel_launch(void* const* d_in, const int* in_sizes, int n_in,
                              void* d_out, int out_size, void* d_ws, size_t ws_size,
                              hipStream_t stream) {
  const float* x     = (const float*)d_in[0];
  const float* ln1_s = (const float*)d_in[1];
  const float* ln1_b = (const float*)d_in[2];
  const float* Wq    = (const float*)d_in[3];
  const float* bq    = (const float*)d_in[4];
  const float* Wk    = (const float*)d_in[5];
  const float* bk    = (const float*)d_in[6];
  const float* Wv    = (const float*)d_in[7];
  const float* bv    = (const float*)d_in[8];
  const float* Wo    = (const float*)d_in[9];
  const float* bo    = (const float*)d_in[10];
  const float* relb  = (const float*)d_in[11];
  const float* ln2_s = (const float*)d_in[12];
  const float* ln2_b = (const float*)d_in[13];
  const float* W1    = (const float*)d_in[14];
  const float* b1    = (const float*)d_in[15];
  const float* W2    = (const float*)d_in[16];
  const float* b2    = (const float*)d_in[17];
  float* out = (float*)d_out;

  // ws layout (~385 MB): bf16 weights 6.3 MB | bqkv 6 KB | y 94.6 MB |
  // x1b 94.6 MB | qkv half-batch 142 MB + ctx 47.3 MB (overlaid by MLP hidden)
  char* ws = (char*)d_ws;
  unsigned short* WqT = (unsigned short*)ws;
  unsigned short* WkT = WqT + 512 * 512;
  unsigned short* WvT = WkT + 512 * 512;  // WqT|WkT|WvT contiguous = [1536][512]
  unsigned short* WoT = WvT + 512 * 512;
  unsigned short* W1T = WoT + 512 * 512;
  unsigned short* W2T = W1T + 512 * 2048;
  float* bqkv = (float*)(W2T + 2048 * 512);
  unsigned short* yb  = (unsigned short*)(bqkv + 1536);  // NTOK*512 bf16
  unsigned short* x1b = yb + (size_t)NTOK * CDIM;        // NTOK*512 bf16
  unsigned short* qkvb = x1b + (size_t)NTOK * CDIM;      // HTOK*1536 bf16
  unsigned short* ctxb = qkvb + (size_t)HTOK * QKVSTR;   // HTOK*512 bf16
  unsigned short* hdn  = qkvb;  // HTOK*2048 bf16, overlays qkv+ctx

  dim3 blk(256);
  transpose_conv<<<dim3(16, 16), blk, 0, stream>>>(Wq, WqT, 512, 512);
  transpose_conv<<<dim3(16, 16), blk, 0, stream>>>(Wk, WkT, 512, 512);
  transpose_conv<<<dim3(16, 16), blk, 0, stream>>>(Wv, WvT, 512, 512);
  transpose_conv<<<dim3(16, 16), blk, 0, stream>>>(Wo, WoT, 512, 512);
  transpose_conv<<<dim3(64, 16), blk, 0, stream>>>(W1, W1T, 512, 2048);
  transpose_conv<<<dim3(16, 64), blk, 0, stream>>>(W2, W2T, 2048, 512);
  concat_bias<<<dim3(6), blk, 0, stream>>>(bq, bk, bv, bqkv);

  ln_f32<<<NTOK / 4, blk, 0, stream>>>(x, ln1_s, ln1_b, yb);

  for (int c = 0; c < 2; ++c) {
    size_t off = (size_t)c * HTOK;
    const unsigned short* yc = yb + off * CDIM;
    gemm_bt<0><<<dim3(361 * 12), blk, 0, stream>>>(yc, WqT, bqkv, nullptr, nullptr,
                                                   qkvb, HTOK, 1536, 512, 12);
    attn_mfma<<<dim3((BATCH / 2) * NHEAD), blk, 0, stream>>>(qkvb, relb, ctxb);
    gemm_bt<2><<<dim3(361 * 4), blk, 0, stream>>>(ctxb, WoT, bo, x + off * CDIM, nullptr,
                                                  x1b + off * CDIM, HTOK, 512, 512, 4);
  }

  ln_bf16<<<NTOK / 4, blk, 0, stream>>>(x1b, ln2_s, ln2_b, yb);

  for (int c = 0; c < 2; ++c) {
    size_t off = (size_t)c * HTOK;
    gemm_bt<1><<<dim3(361 * 16), blk, 0, stream>>>(yb + off * CDIM, W1T, b1, nullptr, nullptr,
                                                   hdn, HTOK, 2048, 512, 16);
    gemm_bt<3><<<dim3(361 * 4), blk, 0, stream>>>(hdn, W2T, b2, nullptr, x1b + off * CDIM,
                                                  out + off * CDIM, HTOK, 512, 2048, 4);
  }
}

// Round 3
// 1716.733 us; speedup vs baseline: 15.3830x; 1.1027x over previous
//
#include <hip/hip_runtime.h>
#include <hip/hip_bf16.h>

#define TOKENS 361
#define CDIM 512
#define NHEAD 8
#define DHEAD 64
#define MLPDIM 2048
#define BATCH 256
#define NTOK (BATCH * TOKENS) /* 92416 */
#define HTOK (NTOK / 2)       /* 46208 = 361*128 */
#define SPAN 37
#define QKVSTR 1536

typedef unsigned int uint32;

typedef __attribute__((ext_vector_type(8))) short bf16x8;
typedef __attribute__((ext_vector_type(4))) float f32x4;

__device__ __forceinline__ unsigned short f2bfu(float f) {
  union { float f; uint32 i; } c; c.f = f;
  uint32 i = c.i;
  uint32 r = (i + 0x7fffu + ((i >> 16) & 1u)) >> 16;
  return (unsigned short)r;
}
__device__ __forceinline__ float bfu2f(unsigned short u) {
  union { uint32 i; float f; } c; c.i = ((uint32)u) << 16; return c.f;
}
__device__ __forceinline__ float lo2f(uint32 u) {
  union { uint32 i; float f; } c; c.i = u << 16; return c.f;
}
__device__ __forceinline__ float hi2f(uint32 u) {
  union { uint32 i; float f; } c; c.i = u & 0xffff0000u; return c.f;
}

// async global->LDS, 16B per lane. LDS dest must be wave-uniform base (+lane*16).
__device__ __forceinline__ void gload16(const void* g, void* l) {
  __builtin_amdgcn_global_load_lds((const __attribute__((address_space(1))) void*)g,
                                   (__attribute__((address_space(3))) void*)l, 16, 0, 0);
}

// ------------------------------------------------- transpose + fp32->bf16
// in fp32 [R, Cc] -> out bf16 [Cc, R]
__global__ __launch_bounds__(256) void transpose_conv(
    const float* __restrict__ in, unsigned short* __restrict__ out, int R, int Cc) {
  __shared__ float tile[32][33];
  int c0 = blockIdx.x * 32, r0 = blockIdx.y * 32;
  int tx = threadIdx.x & 31, ty = threadIdx.x >> 5;
#pragma unroll
  for (int i = 0; i < 32; i += 8)
    tile[ty + i][tx] = in[(size_t)(r0 + ty + i) * Cc + c0 + tx];
  __syncthreads();
#pragma unroll
  for (int i = 0; i < 32; i += 8)
    out[(size_t)(c0 + ty + i) * R + r0 + tx] = f2bfu(tile[tx][ty + i]);
}

// ------------------------------------------------- concat q/k/v biases
__global__ __launch_bounds__(256) void concat_bias(
    const float* __restrict__ a, const float* __restrict__ b,
    const float* __restrict__ c, float* __restrict__ o) {
  int i = blockIdx.x * 256 + threadIdx.x;
  o[i] = i < 512 ? a[i] : (i < 1024 ? b[i - 512] : c[i - 1024]);
}

// ------------------------------------------------- fused LayerNorm fp32 -> bf16
__global__ __launch_bounds__(256) void ln_f32(
    const float* __restrict__ x, const float* __restrict__ sc,
    const float* __restrict__ bs, unsigned short* __restrict__ y) {
  int token = blockIdx.x * 4 + (threadIdx.x >> 6);
  int lane = threadIdx.x & 63;
  const float4* xp = (const float4*)(x + (size_t)token * CDIM + lane * 8);
  float4 f0 = xp[0], f1 = xp[1];
  float v[8] = {f0.x, f0.y, f0.z, f0.w, f1.x, f1.y, f1.z, f1.w};
  float sum = 0.f, sumsq = 0.f;
#pragma unroll
  for (int j = 0; j < 8; ++j) { sum += v[j]; sumsq += v[j] * v[j]; }
#pragma unroll
  for (int off = 1; off < 64; off <<= 1) {
    sum += __shfl_xor(sum, off);
    sumsq += __shfl_xor(sumsq, off);
  }
  float mu = sum * (1.f / 512.f);
  float var = sumsq * (1.f / 512.f) - mu * mu;
  float rs = rsqrtf(var + 1e-6f);
  const float4* sp = (const float4*)(sc + lane * 8);
  const float4* bp = (const float4*)(bs + lane * 8);
  float4 s0 = sp[0], s1 = sp[1], b0 = bp[0], b1 = bp[1];
  float sv[8] = {s0.x, s0.y, s0.z, s0.w, s1.x, s1.y, s1.z, s1.w};
  float bv[8] = {b0.x, b0.y, b0.z, b0.w, b1.x, b1.y, b1.z, b1.w};
  uint32 ov[4];
#pragma unroll
  for (int j = 0; j < 4; ++j) {
    float o0 = (v[2 * j] - mu) * rs * sv[2 * j] + bv[2 * j];
    float o1 = (v[2 * j + 1] - mu) * rs * sv[2 * j + 1] + bv[2 * j + 1];
    ov[j] = (uint32)f2bfu(o0) | ((uint32)f2bfu(o1) << 16);
  }
  uint4 outv = {ov[0], ov[1], ov[2], ov[3]};
  *(uint4*)(y + (size_t)token * CDIM + lane * 8) = outv;
}

// ------------------------------------------------- fused LayerNorm bf16 -> bf16
__global__ __launch_bounds__(256) void ln_bf16(
    const unsigned short* __restrict__ x, const float* __restrict__ sc,
    const float* __restrict__ bs, unsigned short* __restrict__ y) {
  int token = blockIdx.x * 4 + (threadIdx.x >> 6);
  int lane = threadIdx.x & 63;
  uint4 pk = *(const uint4*)(x + (size_t)token * CDIM + lane * 8);
  uint32 uu[4] = {pk.x, pk.y, pk.z, pk.w};
  float v[8];
#pragma unroll
  for (int j = 0; j < 4; ++j) { v[2 * j] = lo2f(uu[j]); v[2 * j + 1] = hi2f(uu[j]); }
  float sum = 0.f, sumsq = 0.f;
#pragma unroll
  for (int j = 0; j < 8; ++j) { sum += v[j]; sumsq += v[j] * v[j]; }
#pragma unroll
  for (int off = 1; off < 64; off <<= 1) {
    sum += __shfl_xor(sum, off);
    sumsq += __shfl_xor(sumsq, off);
  }
  float mu = sum * (1.f / 512.f);
  float var = sumsq * (1.f / 512.f) - mu * mu;
  float rs = rsqrtf(var + 1e-6f);
  const float4* sp = (const float4*)(sc + lane * 8);
  const float4* bp = (const float4*)(bs + lane * 8);
  float4 s0 = sp[0], s1 = sp[1], b0 = bp[0], b1 = bp[1];
  float sv[8] = {s0.x, s0.y, s0.z, s0.w, s1.x, s1.y, s1.z, s1.w};
  float bv[8] = {b0.x, b0.y, b0.z, b0.w, b1.x, b1.y, b1.z, b1.w};
  uint32 ov[4];
#pragma unroll
  for (int j = 0; j < 4; ++j) {
    float o0 = (v[2 * j] - mu) * rs * sv[2 * j] + bv[2 * j];
    float o1 = (v[2 * j + 1] - mu) * rs * sv[2 * j + 1] + bv[2 * j + 1];
    ov[j] = (uint32)f2bfu(o0) | ((uint32)f2bfu(o1) << 16);
  }
  uint4 outv = {ov[0], ov[1], ov[2], ov[3]};
  *(uint4*)(y + (size_t)token * CDIM + lane * 8) = outv;
}

__device__ __forceinline__ float gelu_tanh(float u) {
  float c2 = 0.7978845608028654f * (u + 0.044715f * u * u * u);
  float e = __expf(2.f * c2);
  float th = 1.f - 2.f / (e + 1.f);
  return 0.5f * u * (1.f + th);
}

// ------------------------------------------------- GEMM (B^T), bf16 MFMA
// C[M,N] = A[M,K] @ B + bias (+epilogue). BT is [N,K] bf16. bias fp32.
// EPI 0: store bf16. EPI 1: gelu, store bf16.
// EPI 2: += resf (fp32), store bf16. EPI 3: += resb (bf16), store fp32.
// 1-D grid, N-fastest logical order, bijective XCD-chunked swizzle (m204).
// 2-phase double-buffered gload_lds staging (T3 minimum recipe), chunk-XOR
// swizzled LDS layout (conflict-free ds_read_b128), LDS-staged coalesced
// epilogue stores for bf16 outputs.
template <int EPI>
__global__ __launch_bounds__(256) void gemm_bt(
    const unsigned short* __restrict__ A, const unsigned short* __restrict__ BT,
    const float* __restrict__ bias, const float* __restrict__ resf,
    const unsigned short* __restrict__ resb, void* __restrict__ Cc,
    int M, int N, int K, int nbx) {
  // SH layout (shorts): As0[4096] | As1[4096] | Bs0[4096] | Bs1[4096] = 32 KB
  // epilogue reuses all of SH as Ct[128][128] bf16 (exactly 32 KB)
  __shared__ unsigned short SH[16384];
  int tid = threadIdx.x;
  int wave = tid >> 6, lane = tid & 63;
  int quad = lane >> 4, l16 = lane & 15;

  // XCD-chunked bijective remap: XCD k gets a contiguous logical chunk.
  int nwg = gridDim.x, bid = blockIdx.x;
  int qq = nwg >> 3, rr = nwg & 7;
  int xcd = bid & 7, loc = bid >> 3;
  int L = (xcd < rr ? xcd * (qq + 1) : rr * (qq + 1) + (xcd - rr) * qq) + loc;
  int m0 = (L / nbx) * 128, n0 = (L % nbx) * 128;
  int wm = (wave >> 1) * 64, wn = (wave & 1) * 64;

  f32x4 acc[4][4];
#pragma unroll
  for (int i = 0; i < 4; ++i)
#pragma unroll
    for (int j = 0; j < 4; ++j) acc[i][j] = (f32x4){0.f, 0.f, 0.f, 0.f};

  // staging: row = tid>>2, 16B chunk = (tid&3) XOR ((row>>1)&3)  [source-side swizzle]
  // LDS dest is linear: slot shorts = tid*8 = wave*512 + lane*8.
  int srow = tid >> 2;
  int schunk = ((tid & 3) ^ ((tid >> 3) & 3)) * 8;
  const unsigned short* gA = A + (size_t)(m0 + srow) * K + schunk;
  const unsigned short* gA2 = gA + (size_t)64 * K;
  const unsigned short* gB = BT + (size_t)(n0 + srow) * K + schunk;
  const unsigned short* gB2 = gB + (size_t)64 * K;

  // prologue: stage tile 0 into buffer 0
  {
    unsigned short* a = SH;
    unsigned short* bS = SH + 8192;
    gload16(gA, a + wave * 512);
    gload16(gA2, a + 2048 + wave * 512);
    gload16(gB, bS + wave * 512);
    gload16(gB2, bS + 2048 + wave * 512);
  }
  __syncthreads();

  int rq = (quad ^ ((l16 >> 1) & 3)) * 8;  // swizzled read-chunk (shorts)
  int cur = 0;
  for (int k0 = 0; k0 < K; k0 += 32) {
    if (k0 + 32 < K) {  // issue next-tile loads into other buffer
      int nb = cur ^ 1;
      unsigned short* a = SH + nb * 4096;
      unsigned short* bS = SH + 8192 + nb * 4096;
      gload16(gA + k0 + 32, a + wave * 512);
      gload16(gA2 + k0 + 32, a + 2048 + wave * 512);
      gload16(gB + k0 + 32, bS + wave * 512);
      gload16(gB2 + k0 + 32, bS + 2048 + wave * 512);
    }
    const unsigned short* As = SH + cur * 4096;
    const unsigned short* Bs = SH + 8192 + cur * 4096;
    bf16x8 af[4], bfr[4];
#pragma unroll
    for (int mi = 0; mi < 4; ++mi)
      af[mi] = *(const bf16x8*)&As[(wm + mi * 16 + l16) * 32 + rq];
#pragma unroll
    for (int ni = 0; ni < 4; ++ni)
      bfr[ni] = *(const bf16x8*)&Bs[(wn + ni * 16 + l16) * 32 + rq];
#pragma unroll
    for (int mi = 0; mi < 4; ++mi)
#pragma unroll
      for (int ni = 0; ni < 4; ++ni)
        acc[mi][ni] = __builtin_amdgcn_mfma_f32_16x16x32_bf16(af[mi], bfr[ni], acc[mi][ni], 0, 0, 0);
    __syncthreads();  // drains next-tile vmcnt + all waves done reading cur
    cur ^= 1;
  }

  unsigned short* o16 = (unsigned short*)Cc;
  float* o32 = (float*)Cc;
  if (EPI == 3) {
    // fp32 output + bf16 residual: scalar path (64 KB tile doesn't fit LDS)
#pragma unroll
    for (int ni = 0; ni < 4; ++ni) {
      int gc = n0 + wn + ni * 16 + l16;
      float bz = bias[gc];
#pragma unroll
      for (int mi = 0; mi < 4; ++mi) {
#pragma unroll
        for (int r = 0; r < 4; ++r) {
          int gr = m0 + wm + mi * 16 + quad * 4 + r;
          float val = acc[mi][ni][r] + bz;
          val += bfu2f(resb[(size_t)gr * N + gc]);
          o32[(size_t)gr * N + gc] = val;
        }
      }
    }
  } else {
    // bf16 output: stage C-tile in LDS, then fully-coalesced dwordx4 stores
#pragma unroll
    for (int ni = 0; ni < 4; ++ni) {
      int gc = n0 + wn + ni * 16 + l16;
      float bz = bias[gc];
#pragma unroll
      for (int mi = 0; mi < 4; ++mi) {
#pragma unroll
        for (int r = 0; r < 4; ++r) {
          int lr = wm + mi * 16 + quad * 4 + r;
          float val = acc[mi][ni][r] + bz;
          if (EPI == 1) val = gelu_tanh(val);
          if (EPI == 2) val += resf[(size_t)(m0 + lr) * N + gc];
          SH[lr * 128 + wn + ni * 16 + l16] = f2bfu(val);
        }
      }
    }
    __syncthreads();
    int tg = tid >> 4, t15 = tid & 15;
#pragma unroll
    for (int j = 0; j < 8; ++j) {
      int row = j * 16 + tg;
      uint4 w = *(const uint4*)&SH[row * 128 + t15 * 8];
      *(uint4*)(o16 + (size_t)(m0 + row) * N + n0 + t15 * 8) = w;
    }
  }
}

// ------------------------------------------------- MFMA attention
// one block (4 waves) per (b,h). qkv packed [HTOK][1536] (q|k|v per row).
#define SROW 72   /* Ks stride, shorts */
#define PSTR 392  /* VT/Ps stride, shorts */
__global__ __launch_bounds__(256, 1) void attn_mfma(
    const unsigned short* __restrict__ qkv, const float* __restrict__ relb,
    unsigned short* __restrict__ ctx) {
  __shared__ unsigned short Ks[368 * SROW];  // 52992 B
  __shared__ unsigned short VT[64 * PSTR];   // 50176 B
  __shared__ unsigned short Ps[64 * PSTR];   // 50176 B
  __shared__ float biasF[1369];
  int b = blockIdx.x >> 3, h = blockIdx.x & 7;
  int tid = threadIdx.x;
  int wave = tid >> 6, lane = tid & 63;
  int quad = lane >> 4, l16 = lane & 15;
  size_t baseq = ((size_t)b * TOKENS) * QKVSTR + h * DHEAD;
  size_t basec = ((size_t)b * TOKENS) * CDIM + h * DHEAD;
  const unsigned short* kp = qkv + baseq + 512;
  const unsigned short* vp = qkv + baseq + 1024;

  // stage K rows (16B chunks, coalesced)
  for (int vv = tid; vv < TOKENS * 8; vv += 256) {
    int r = vv >> 3, c = (vv & 7) * 8;
    *(uint4*)&Ks[r * SROW + c] = *(const uint4*)(kp + (size_t)r * QKVSTR + c);
  }
  if (tid < 56) {  // zero pad rows 361..367
    int r = 361 + (tid >> 3), c = (tid & 7) * 8;
    *(uint4*)&Ks[r * SROW + c] = (uint4){0u, 0u, 0u, 0u};
  }
  // stage V transposed: VT[d][s]
  for (int vv = tid; vv < TOKENS * 8; vv += 256) {
    int s = vv >> 3, c = (vv & 7) * 8;
    uint4 pk = *(const uint4*)(vp + (size_t)s * QKVSTR + c);
    unsigned short* dst = &VT[c * PSTR + s];
    uint32 w0 = pk.x, w1 = pk.y, w2 = pk.z, w3 = pk.w;
    dst[0]        = (unsigned short)w0;  dst[PSTR]     = (unsigned short)(w0 >> 16);
    dst[2 * PSTR] = (unsigned short)w1;  dst[3 * PSTR] = (unsigned short)(w1 >> 16);
    dst[4 * PSTR] = (unsigned short)w2;  dst[5 * PSTR] = (unsigned short)(w2 >> 16);
    dst[6 * PSTR] = (unsigned short)w3;  dst[7 * PSTR] = (unsigned short)(w3 >> 16);
  }
  for (int vv = tid; vv < 64 * 23; vv += 256) {
    int s = 361 + (vv >> 6), d = vv & 63;
    VT[d * PSTR + s] = 0;
  }
  for (int i = tid; i < 1369; i += 256) biasF[i] = relb[h * 1369 + i];
  for (int i = lane; i < 256; i += 64) {
    int rrp = i >> 4, cc = i & 15;
    Ps[(wave * 16 + rrp) * PSTR + 368 + cc] = 0;
  }
  __syncthreads();

  for (int t0 = 0; t0 < TOKENS; t0 += 64) {
    int rowb = t0 + wave * 16;
    const unsigned short* qrow = qkv + baseq + (size_t)(rowb + l16) * QKVSTR + quad * 8;
    bf16x8 aq0 = *(const bf16x8*)(qrow);
    bf16x8 aq1 = *(const bf16x8*)(qrow + 32);
    int tb[4];
#pragma unroll
    for (int r = 0; r < 4; ++r) {
      int t = rowb + quad * 4 + r;
      if (t > 360) t = 360;
      int rt = t / 19, ct = t - rt * 19;
      tb[r] = rt * SPAN + ct + (18 * SPAN + 18);
    }
    // ---- S = Q K^T
    f32x4 sc[23];
#pragma unroll
    for (int n = 0; n < 23; ++n) {
      const unsigned short* kr = &Ks[(n * 16 + l16) * SROW + quad * 8];
      bf16x8 b0 = *(const bf16x8*)kr;
      bf16x8 b1 = *(const bf16x8*)(kr + 32);
      f32x4 a = {0.f, 0.f, 0.f, 0.f};
      a = __builtin_amdgcn_mfma_f32_16x16x32_bf16(aq0, b0, a, 0, 0, 0);
      a = __builtin_amdgcn_mfma_f32_16x16x32_bf16(aq1, b1, a, 0, 0, 0);
      sc[n] = a;
    }
    // ---- scale + rel-bias + row max
    float mx[4] = {-1e30f, -1e30f, -1e30f, -1e30f};
#pragma unroll
    for (int n = 0; n < 23; ++n) {
      int s = n * 16 + l16;
      int sv = s > 360 ? 360 : s;
      int rs = sv / 19, cs = sv - rs * 19;
      int sb = rs * SPAN + cs;
#pragma unroll
      for (int r = 0; r < 4; ++r) {
        float val = sc[n][r] * 0.125f + biasF[tb[r] - sb];
        if (s > 360) val = -1e30f;
        sc[n][r] = val;
        mx[r] = fmaxf(mx[r], val);
      }
    }
#pragma unroll
    for (int off = 1; off < 16; off <<= 1)
#pragma unroll
      for (int r = 0; r < 4; ++r) mx[r] = fmaxf(mx[r], __shfl_xor(mx[r], off));
    // ---- exp + row sum
    float sm[4] = {0.f, 0.f, 0.f, 0.f};
#pragma unroll
    for (int n = 0; n < 23; ++n)
#pragma unroll
      for (int r = 0; r < 4; ++r) {
        float p = __expf(sc[n][r] - mx[r]);
        sc[n][r] = p;
        sm[r] += p;
      }
#pragma unroll
    for (int off = 1; off < 16; off <<= 1)
#pragma unroll
      for (int r = 0; r < 4; ++r) sm[r] += __shfl_xor(sm[r], off);
    float inv[4];
#pragma unroll
    for (int r = 0; r < 4; ++r) inv[r] = 1.f / sm[r];
#pragma unroll
    for (int n = 0; n < 23; ++n)
#pragma unroll
      for (int r = 0; r < 4; ++r)
        Ps[(wave * 16 + quad * 4 + r) * PSTR + n * 16 + l16] = f2bfu(sc[n][r] * inv[r]);
    // ---- ctx = P @ V
    f32x4 pacc[4];
#pragma unroll
    for (int ni = 0; ni < 4; ++ni) pacc[ni] = (f32x4){0.f, 0.f, 0.f, 0.f};
#pragma unroll
    for (int kk = 0; kk < 12; ++kk) {
      bf16x8 pa = *(const bf16x8*)&Ps[(wave * 16 + l16) * PSTR + kk * 32 + quad * 8];
#pragma unroll
      for (int ni = 0; ni < 4; ++ni) {
        bf16x8 vb = *(const bf16x8*)&VT[(ni * 16 + l16) * PSTR + kk * 32 + quad * 8];
        pacc[ni] = __builtin_amdgcn_mfma_f32_16x16x32_bf16(pa, vb, pacc[ni], 0, 0, 0);
      }
    }
#pragma unroll
    for (int ni = 0; ni < 4; ++ni)
#pragma unroll
      for (int r = 0; r < 4; ++r) {
        int t = rowb + quad * 4 + r;
        if (t < TOKENS)
          ctx[basec + (size_t)t * CDIM + ni * 16 + l16] = f2bfu(pacc[ni][r]);
      }
  }
}

// ------------------------------------------------- launch
extern "C" void kernel_launch(void* const* d_in, const int* in_sizes, int n_in,
                              void* d_out, int out_size, void* d_ws, size_t ws_size,
                              hipStream_t stream) {
  const float* x     = (const float*)d_in[0];
  const float* ln1_s = (const float*)d_in[1];
  const float* ln1_b = (const float*)d_in[2];
  const float* Wq    = (const float*)d_in[3];
  const float* bq    = (const float*)d_in[4];
  const float* Wk    = (const float*)d_in[5];
  const float* bk    = (const float*)d_in[6];
  const float* Wv    = (const float*)d_in[7];
  const float* bv    = (const float*)d_in[8];
  const float* Wo    = (const float*)d_in[9];
  const float* bo    = (const float*)d_in[10];
  const float* relb  = (const float*)d_in[11];
  const float* ln2_s = (const float*)d_in[12];
  const float* ln2_b = (const float*)d_in[13];
  const float* W1    = (const float*)d_in[14];
  const float* b1    = (const float*)d_in[15];
  const float* W2    = (const float*)d_in[16];
  const float* b2    = (const float*)d_in[17];
  float* out = (float*)d_out;

  // ws layout (~385 MB): bf16 weights 6.3 MB | bqkv 6 KB | y 94.6 MB |
  // x1b 94.6 MB | qkv half-batch 142 MB + ctx 47.3 MB (overlaid by MLP hidden)
  char* ws = (char*)d_ws;
  unsigned short* WqT = (unsigned short*)ws;
  unsigned short* WkT = WqT + 512 * 512;
  unsigned short* WvT = WkT + 512 * 512;  // WqT|WkT|WvT contiguous = [1536][512]
  unsigned short* WoT = WvT + 512 * 512;
  unsigned short* W1T = WoT + 512 * 512;
  unsigned short* W2T = W1T + 512 * 2048;
  float* bqkv = (float*)(W2T + 2048 * 512);
  unsigned short* yb  = (unsigned short*)(bqkv + 1536);  // NTOK*512 bf16
  unsigned short* x1b = yb + (size_t)NTOK * CDIM;        // NTOK*512 bf16
  unsigned short* qkvb = x1b + (size_t)NTOK * CDIM;      // HTOK*1536 bf16
  unsigned short* ctxb = qkvb + (size_t)HTOK * QKVSTR;   // HTOK*512 bf16
  unsigned short* hdn  = qkvb;  // HTOK*2048 bf16, overlays qkv+ctx

  dim3 blk(256);
  transpose_conv<<<dim3(16, 16), blk, 0, stream>>>(Wq, WqT, 512, 512);
  transpose_conv<<<dim3(16, 16), blk, 0, stream>>>(Wk, WkT, 512, 512);
  transpose_conv<<<dim3(16, 16), blk, 0, stream>>>(Wv, WvT, 512, 512);
  transpose_conv<<<dim3(16, 16), blk, 0, stream>>>(Wo, WoT, 512, 512);
  transpose_conv<<<dim3(64, 16), blk, 0, stream>>>(W1, W1T, 512, 2048);
  transpose_conv<<<dim3(16, 64), blk, 0, stream>>>(W2, W2T, 2048, 512);
  concat_bias<<<dim3(6), blk, 0, stream>>>(bq, bk, bv, bqkv);

  ln_f32<<<NTOK / 4, blk, 0, stream>>>(x, ln1_s, ln1_b, yb);

  for (int c = 0; c < 2; ++c) {
    size_t off = (size_t)c * HTOK;
    const unsigned short* yc = yb + off * CDIM;
    gemm_bt<0><<<dim3(361 * 12), blk, 0, stream>>>(yc, WqT, bqkv, nullptr, nullptr,
                                                   qkvb, HTOK, 1536, 512, 12);
    attn_mfma<<<dim3((BATCH / 2) * NHEAD), blk, 0, stream>>>(qkvb, relb, ctxb);
    gemm_bt<2><<<dim3(361 * 4), blk, 0, stream>>>(ctxb, WoT, bo, x + off * CDIM, nullptr,
                                                  x1b + off * CDIM, HTOK, 512, 512, 4);
  }

  ln_bf16<<<NTOK / 4, blk, 0, stream>>>(x1b, ln2_s, ln2_b, yb);

  for (int c = 0; c < 2; ++c) {
    size_t off = (size_t)c * HTOK;
    gemm_bt<1><<<dim3(361 * 16), blk, 0, stream>>>(yb + off * CDIM, W1T, b1, nullptr, nullptr,
                                                   hdn, HTOK, 2048, 512, 16);
    gemm_bt<3><<<dim3(361 * 4), blk, 0, stream>>>(hdn, W2T, b2, nullptr, x1b + off * CDIM,
                                                  out + off * CDIM, HTOK, 512, 2048, 4);
  }
}

// Round 4
// 1556.532 us; speedup vs baseline: 16.9663x; 1.1029x over previous
//
#include <hip/hip_runtime.h>
#include <hip/hip_bf16.h>

#define TOKENS 361
#define CDIM 512
#define NHEAD 8
#define DHEAD 64
#define MLPDIM 2048
#define BATCH 256
#define NTOK (BATCH * TOKENS) /* 92416 */
#define HTOK (NTOK / 2)       /* 46208 = 361*128 */
#define SPAN 37
#define QKVSTR 1536

typedef unsigned int uint32;

typedef __attribute__((ext_vector_type(8))) short bf16x8;
typedef __attribute__((ext_vector_type(4))) float f32x4;

__device__ __forceinline__ unsigned short f2bfu(float f) {
  union { float f; uint32 i; } c; c.f = f;
  uint32 i = c.i;
  uint32 r = (i + 0x7fffu + ((i >> 16) & 1u)) >> 16;
  return (unsigned short)r;
}
__device__ __forceinline__ float bfu2f(unsigned short u) {
  union { uint32 i; float f; } c; c.i = ((uint32)u) << 16; return c.f;
}
__device__ __forceinline__ float lo2f(uint32 u) {
  union { uint32 i; float f; } c; c.i = u << 16; return c.f;
}
__device__ __forceinline__ float hi2f(uint32 u) {
  union { uint32 i; float f; } c; c.i = u & 0xffff0000u; return c.f;
}

// async global->LDS, 16B per lane. LDS dest must be wave-uniform base (+lane*16).
__device__ __forceinline__ void gload16(const void* g, void* l) {
  __builtin_amdgcn_global_load_lds((const __attribute__((address_space(1))) void*)g,
                                   (__attribute__((address_space(3))) void*)l, 16, 0, 0);
}

// ------------------------------------------------- transpose + fp32->bf16
// in fp32 [R, Cc] -> out bf16 [Cc, R]
__global__ __launch_bounds__(256) void transpose_conv(
    const float* __restrict__ in, unsigned short* __restrict__ out, int R, int Cc) {
  __shared__ float tile[32][33];
  int c0 = blockIdx.x * 32, r0 = blockIdx.y * 32;
  int tx = threadIdx.x & 31, ty = threadIdx.x >> 5;
#pragma unroll
  for (int i = 0; i < 32; i += 8)
    tile[ty + i][tx] = in[(size_t)(r0 + ty + i) * Cc + c0 + tx];
  __syncthreads();
#pragma unroll
  for (int i = 0; i < 32; i += 8)
    out[(size_t)(c0 + ty + i) * R + r0 + tx] = f2bfu(tile[tx][ty + i]);
}

// ------------------------------------------------- concat q/k/v biases
__global__ __launch_bounds__(256) void concat_bias(
    const float* __restrict__ a, const float* __restrict__ b,
    const float* __restrict__ c, float* __restrict__ o) {
  int i = blockIdx.x * 256 + threadIdx.x;
  o[i] = i < 512 ? a[i] : (i < 1024 ? b[i - 512] : c[i - 1024]);
}

// ------------------------------------------------- fused LayerNorm fp32 -> bf16
__global__ __launch_bounds__(256) void ln_f32(
    const float* __restrict__ x, const float* __restrict__ sc,
    const float* __restrict__ bs, unsigned short* __restrict__ y) {
  int token = blockIdx.x * 4 + (threadIdx.x >> 6);
  int lane = threadIdx.x & 63;
  const float4* xp = (const float4*)(x + (size_t)token * CDIM + lane * 8);
  float4 f0 = xp[0], f1 = xp[1];
  float v[8] = {f0.x, f0.y, f0.z, f0.w, f1.x, f1.y, f1.z, f1.w};
  float sum = 0.f, sumsq = 0.f;
#pragma unroll
  for (int j = 0; j < 8; ++j) { sum += v[j]; sumsq += v[j] * v[j]; }
#pragma unroll
  for (int off = 1; off < 64; off <<= 1) {
    sum += __shfl_xor(sum, off);
    sumsq += __shfl_xor(sumsq, off);
  }
  float mu = sum * (1.f / 512.f);
  float var = sumsq * (1.f / 512.f) - mu * mu;
  float rs = rsqrtf(var + 1e-6f);
  const float4* sp = (const float4*)(sc + lane * 8);
  const float4* bp = (const float4*)(bs + lane * 8);
  float4 s0 = sp[0], s1 = sp[1], b0 = bp[0], b1 = bp[1];
  float sv[8] = {s0.x, s0.y, s0.z, s0.w, s1.x, s1.y, s1.z, s1.w};
  float bv[8] = {b0.x, b0.y, b0.z, b0.w, b1.x, b1.y, b1.z, b1.w};
  uint32 ov[4];
#pragma unroll
  for (int j = 0; j < 4; ++j) {
    float o0 = (v[2 * j] - mu) * rs * sv[2 * j] + bv[2 * j];
    float o1 = (v[2 * j + 1] - mu) * rs * sv[2 * j + 1] + bv[2 * j + 1];
    ov[j] = (uint32)f2bfu(o0) | ((uint32)f2bfu(o1) << 16);
  }
  uint4 outv = {ov[0], ov[1], ov[2], ov[3]};
  *(uint4*)(y + (size_t)token * CDIM + lane * 8) = outv;
}

// ------------------------------------------------- fused LayerNorm bf16 -> bf16
__global__ __launch_bounds__(256) void ln_bf16(
    const unsigned short* __restrict__ x, const float* __restrict__ sc,
    const float* __restrict__ bs, unsigned short* __restrict__ y) {
  int token = blockIdx.x * 4 + (threadIdx.x >> 6);
  int lane = threadIdx.x & 63;
  uint4 pk = *(const uint4*)(x + (size_t)token * CDIM + lane * 8);
  uint32 uu[4] = {pk.x, pk.y, pk.z, pk.w};
  float v[8];
#pragma unroll
  for (int j = 0; j < 4; ++j) { v[2 * j] = lo2f(uu[j]); v[2 * j + 1] = hi2f(uu[j]); }
  float sum = 0.f, sumsq = 0.f;
#pragma unroll
  for (int j = 0; j < 8; ++j) { sum += v[j]; sumsq += v[j] * v[j]; }
#pragma unroll
  for (int off = 1; off < 64; off <<= 1) {
    sum += __shfl_xor(sum, off);
    sumsq += __shfl_xor(sumsq, off);
  }
  float mu = sum * (1.f / 512.f);
  float var = sumsq * (1.f / 512.f) - mu * mu;
  float rs = rsqrtf(var + 1e-6f);
  const float4* sp = (const float4*)(sc + lane * 8);
  const float4* bp = (const float4*)(bs + lane * 8);
  float4 s0 = sp[0], s1 = sp[1], b0 = bp[0], b1 = bp[1];
  float sv[8] = {s0.x, s0.y, s0.z, s0.w, s1.x, s1.y, s1.z, s1.w};
  float bv[8] = {b0.x, b0.y, b0.z, b0.w, b1.x, b1.y, b1.z, b1.w};
  uint32 ov[4];
#pragma unroll
  for (int j = 0; j < 4; ++j) {
    float o0 = (v[2 * j] - mu) * rs * sv[2 * j] + bv[2 * j];
    float o1 = (v[2 * j + 1] - mu) * rs * sv[2 * j + 1] + bv[2 * j + 1];
    ov[j] = (uint32)f2bfu(o0) | ((uint32)f2bfu(o1) << 16);
  }
  uint4 outv = {ov[0], ov[1], ov[2], ov[3]};
  *(uint4*)(y + (size_t)token * CDIM + lane * 8) = outv;
}

__device__ __forceinline__ float gelu_tanh(float u) {
  float c2 = 0.7978845608028654f * (u + 0.044715f * u * u * u);
  float e = __expf(2.f * c2);
  float th = 1.f - 2.f / (e + 1.f);
  return 0.5f * u * (1.f + th);
}

// ------------------------------------------------- GEMM (B^T), bf16 MFMA
// C[M,N] = A[M,K] @ B + bias (+epilogue). BT is [N,K] bf16. bias fp32.
// EPI 0: store bf16. EPI 1: gelu, store bf16.
// EPI 2: += resf (fp32), store bf16. EPI 3: += resb (bf16), store fp32.
// 1-D grid, N-fastest logical order, bijective XCD-chunked swizzle (m204).
// 2-phase double-buffered gload_lds staging, chunk-XOR swizzled LDS layout,
// LDS-staged coalesced epilogue stores (bf16: whole tile; fp32: two halves).
template <int EPI>
__global__ __launch_bounds__(256) void gemm_bt(
    const unsigned short* __restrict__ A, const unsigned short* __restrict__ BT,
    const float* __restrict__ bias, const float* __restrict__ resf,
    const unsigned short* __restrict__ resb, void* __restrict__ Cc,
    int M, int N, int K, int nbx) {
  // SH layout (shorts): As0[4096] | As1[4096] | Bs0[4096] | Bs1[4096] = 32 KB
  // epilogue reuses SH: bf16 C[128][128] (32 KB) or fp32 C-half [128][64] (32 KB)
  __shared__ unsigned short SH[16384];
  int tid = threadIdx.x;
  int wave = tid >> 6, lane = tid & 63;
  int quad = lane >> 4, l16 = lane & 15;

  // XCD-chunked bijective remap: XCD k gets a contiguous logical chunk.
  int nwg = gridDim.x, bid = blockIdx.x;
  int qq = nwg >> 3, rr = nwg & 7;
  int xcd = bid & 7, loc = bid >> 3;
  int L = (xcd < rr ? xcd * (qq + 1) : rr * (qq + 1) + (xcd - rr) * qq) + loc;
  int m0 = (L / nbx) * 128, n0 = (L % nbx) * 128;
  int wm = (wave >> 1) * 64, wn = (wave & 1) * 64;

  f32x4 acc[4][4];
#pragma unroll
  for (int i = 0; i < 4; ++i)
#pragma unroll
    for (int j = 0; j < 4; ++j) acc[i][j] = (f32x4){0.f, 0.f, 0.f, 0.f};

  // staging: row = tid>>2, 16B chunk = (tid&3) XOR ((row>>1)&3)  [source-side swizzle]
  // LDS dest is linear: slot shorts = tid*8 = wave*512 + lane*8.
  int srow = tid >> 2;
  int schunk = ((tid & 3) ^ ((tid >> 3) & 3)) * 8;
  const unsigned short* gA = A + (size_t)(m0 + srow) * K + schunk;
  const unsigned short* gA2 = gA + (size_t)64 * K;
  const unsigned short* gB = BT + (size_t)(n0 + srow) * K + schunk;
  const unsigned short* gB2 = gB + (size_t)64 * K;

  // prologue: stage tile 0 into buffer 0
  {
    unsigned short* a = SH;
    unsigned short* bS = SH + 8192;
    gload16(gA, a + wave * 512);
    gload16(gA2, a + 2048 + wave * 512);
    gload16(gB, bS + wave * 512);
    gload16(gB2, bS + 2048 + wave * 512);
  }
  __syncthreads();

  int rq = (quad ^ ((l16 >> 1) & 3)) * 8;  // swizzled read-chunk (shorts)
  int cur = 0;
  for (int k0 = 0; k0 < K; k0 += 32) {
    if (k0 + 32 < K) {  // issue next-tile loads into other buffer
      int nb = cur ^ 1;
      unsigned short* a = SH + nb * 4096;
      unsigned short* bS = SH + 8192 + nb * 4096;
      gload16(gA + k0 + 32, a + wave * 512);
      gload16(gA2 + k0 + 32, a + 2048 + wave * 512);
      gload16(gB + k0 + 32, bS + wave * 512);
      gload16(gB2 + k0 + 32, bS + 2048 + wave * 512);
    }
    const unsigned short* As = SH + cur * 4096;
    const unsigned short* Bs = SH + 8192 + cur * 4096;
    bf16x8 af[4], bfr[4];
#pragma unroll
    for (int mi = 0; mi < 4; ++mi)
      af[mi] = *(const bf16x8*)&As[(wm + mi * 16 + l16) * 32 + rq];
#pragma unroll
    for (int ni = 0; ni < 4; ++ni)
      bfr[ni] = *(const bf16x8*)&Bs[(wn + ni * 16 + l16) * 32 + rq];
#pragma unroll
    for (int mi = 0; mi < 4; ++mi)
#pragma unroll
      for (int ni = 0; ni < 4; ++ni)
        acc[mi][ni] = __builtin_amdgcn_mfma_f32_16x16x32_bf16(af[mi], bfr[ni], acc[mi][ni], 0, 0, 0);
    __syncthreads();  // drains next-tile vmcnt + all waves done reading cur
    cur ^= 1;
  }

  unsigned short* o16 = (unsigned short*)Cc;
  float* o32 = (float*)Cc;
  if (EPI == 3) {
    // fp32 output + bf16 residual: stage in LDS as two 128x64 fp32 halves,
    // residual added in the coalesced store phase.
    float* SHf = (float*)SH;
#pragma unroll
    for (int h2 = 0; h2 < 2; ++h2) {
      __syncthreads();
      if ((wn >> 6) == h2) {
#pragma unroll
        for (int ni = 0; ni < 4; ++ni) {
          float bz = bias[n0 + h2 * 64 + ni * 16 + l16];
#pragma unroll
          for (int mi = 0; mi < 4; ++mi) {
#pragma unroll
            for (int r = 0; r < 4; ++r) {
              int row = wm + mi * 16 + quad * 4 + r;
              SHf[row * 64 + ni * 16 + l16] = acc[mi][ni][r] + bz;
            }
          }
        }
      }
      __syncthreads();
#pragma unroll
      for (int j = 0; j < 8; ++j) {
        int idx = j * 256 + tid;
        int row = idx >> 4, c4 = (idx & 15) * 4;
        size_t goff = (size_t)(m0 + row) * N + n0 + h2 * 64 + c4;
        uint2 rb = *(const uint2*)(resb + goff);
        float4 sv = *(const float4*)&SHf[row * 64 + c4];
        sv.x += lo2f(rb.x); sv.y += hi2f(rb.x);
        sv.z += lo2f(rb.y); sv.w += hi2f(rb.y);
        *(float4*)(o32 + goff) = sv;
      }
    }
  } else {
    // bf16 output: stage C-tile in LDS, then fully-coalesced dwordx4 stores
#pragma unroll
    for (int ni = 0; ni < 4; ++ni) {
      int gc = n0 + wn + ni * 16 + l16;
      float bz = bias[gc];
#pragma unroll
      for (int mi = 0; mi < 4; ++mi) {
#pragma unroll
        for (int r = 0; r < 4; ++r) {
          int lr = wm + mi * 16 + quad * 4 + r;
          float val = acc[mi][ni][r] + bz;
          if (EPI == 1) val = gelu_tanh(val);
          if (EPI == 2) val += resf[(size_t)(m0 + lr) * N + gc];
          SH[lr * 128 + wn + ni * 16 + l16] = f2bfu(val);
        }
      }
    }
    __syncthreads();
    int tg = tid >> 4, t15 = tid & 15;
#pragma unroll
    for (int j = 0; j < 8; ++j) {
      int row = j * 16 + tg;
      uint4 w = *(const uint4*)&SH[row * 128 + t15 * 8];
      *(uint4*)(o16 + (size_t)(m0 + row) * N + n0 + t15 * 8) = w;
    }
  }
}

// ------------------------------------------------- MFMA attention
// one block (8 waves, 512 thr) per (b,h). qkv packed [HTOK][1536].
// K [384x64] and V^T [64x384] in LDS with XOR-granule swizzle (16B granule
// index ^= row&7 -> conflict-free b128 fragment reads). Each wave owns 16
// q-rows; 3 iters of 128 rows. P normalized bf16 -> Ps[128][128] (wave-private
// rows, col-chunked x3), PV accumulates across chunks.
#define KROW 64   /* Ks row stride, shorts */
#define VROW 384  /* VT row stride, shorts */
#define PROW 128  /* Ps row stride, shorts */
__global__ __launch_bounds__(512, 1) void attn_mfma(
    const unsigned short* __restrict__ qkv, const float* __restrict__ relb,
    unsigned short* __restrict__ ctx) {
  __shared__ unsigned short Ks[384 * KROW];  // 49152 B
  __shared__ unsigned short VT[64 * VROW];   // 49152 B
  __shared__ unsigned short Ps[128 * PROW];  // 32768 B
  __shared__ float biasF[1369];              //  5476 B -> 136548 B total
  int b = blockIdx.x >> 3, h = blockIdx.x & 7;
  int tid = threadIdx.x;
  int wave = tid >> 6, lane = tid & 63;
  int quad = lane >> 4, l16 = lane & 15;
  int l8 = l16 & 7;
  size_t baseq = ((size_t)b * TOKENS) * QKVSTR + h * DHEAD;
  size_t basec = ((size_t)b * TOKENS) * CDIM + h * DHEAD;
  const unsigned short* kp = qkv + baseq + 512;
  const unsigned short* vp = qkv + baseq + 1024;

  // stage K rows 0..360 swizzled; zero rows 361..383
  for (int vv = tid; vv < 384 * 8; vv += 512) {
    int r = vv >> 3, c8 = vv & 7;
    uint4 val = (uint4){0u, 0u, 0u, 0u};
    if (r < TOKENS) val = *(const uint4*)(kp + (size_t)r * QKVSTR + c8 * 8);
    *(uint4*)&Ks[r * KROW + ((c8 ^ (r & 7)) << 3)] = val;
  }
  // stage V transposed + swizzled: VT[d][s]
  for (int vv = tid; vv < TOKENS * 8; vv += 512) {
    int s = vv >> 3, c = (vv & 7) * 8;
    uint4 pk = *(const uint4*)(vp + (size_t)s * QKVSTR + c);
    uint32 w[4] = {pk.x, pk.y, pk.z, pk.w};
    int g0 = s >> 3, s7 = s & 7;
#pragma unroll
    for (int j = 0; j < 8; ++j) {
      unsigned short hv = (unsigned short)(w[j >> 1] >> ((j & 1) * 16));
      int d0 = c + j;
      VT[d0 * VROW + ((g0 ^ (d0 & 7)) << 3) + s7] = hv;
    }
  }
  // zero pad VT cols 361..383
  for (int vv = tid; vv < 64 * 23; vv += 512) {
    int s = 361 + (vv >> 6), d = vv & 63;
    VT[d * VROW + (((s >> 3) ^ (d & 7)) << 3) + (s & 7)] = 0;
  }
  for (int i = tid; i < 1369; i += 512) biasF[i] = relb[h * 1369 + i];
  __syncthreads();

  for (int it = 0; it < 3; ++it) {
    int rowb = it * 128 + wave * 16;
    const unsigned short* qrow = qkv + baseq + (size_t)(rowb + l16) * QKVSTR + quad * 8;
    bf16x8 aq0 = *(const bf16x8*)(qrow);
    bf16x8 aq1 = *(const bf16x8*)(qrow + 32);
    int tb[4];
#pragma unroll
    for (int r = 0; r < 4; ++r) {
      int t = rowb + quad * 4 + r;
      if (t > 360) t = 360;  // clamp garbage rows: keeps bias index in range
      int rt = t / 19, ct = t - rt * 19;
      tb[r] = rt * SPAN + ct + (18 * SPAN + 18);
    }
    // ---- S = Q K^T over 24 column tiles (register resident)
    f32x4 sc[24];
    __builtin_amdgcn_s_setprio(1);
#pragma unroll
    for (int n = 0; n < 24; ++n) {
      const unsigned short* kr = &Ks[(n * 16 + l16) * KROW];
      bf16x8 b0 = *(const bf16x8*)(kr + ((quad ^ l8) << 3));
      bf16x8 b1 = *(const bf16x8*)(kr + (((quad + 4) ^ l8) << 3));
      f32x4 a = {0.f, 0.f, 0.f, 0.f};
      a = __builtin_amdgcn_mfma_f32_16x16x32_bf16(aq0, b0, a, 0, 0, 0);
      a = __builtin_amdgcn_mfma_f32_16x16x32_bf16(aq1, b1, a, 0, 0, 0);
      sc[n] = a;
    }
    __builtin_amdgcn_s_setprio(0);
    // ---- scale + rel-bias + row max
    float mx[4] = {-1e30f, -1e30f, -1e30f, -1e30f};
#pragma unroll
    for (int n = 0; n < 24; ++n) {
      int s = n * 16 + l16;
      int sv = s > 360 ? 360 : s;
      int rs = sv / 19, cs = sv - rs * 19;
      int sb = rs * SPAN + cs;
#pragma unroll
      for (int r = 0; r < 4; ++r) {
        float val = sc[n][r] * 0.125f + biasF[tb[r] - sb];
        if (s > 360) val = -1e30f;
        sc[n][r] = val;
        mx[r] = fmaxf(mx[r], val);
      }
    }
#pragma unroll
    for (int off = 1; off < 16; off <<= 1)
#pragma unroll
      for (int r = 0; r < 4; ++r) mx[r] = fmaxf(mx[r], __shfl_xor(mx[r], off));
    // ---- exp + row sum
    float sm[4] = {0.f, 0.f, 0.f, 0.f};
#pragma unroll
    for (int n = 0; n < 24; ++n)
#pragma unroll
      for (int r = 0; r < 4; ++r) {
        float p = __expf(sc[n][r] - mx[r]);
        sc[n][r] = p;
        sm[r] += p;
      }
#pragma unroll
    for (int off = 1; off < 16; off <<= 1)
#pragma unroll
      for (int r = 0; r < 4; ++r) sm[r] += __shfl_xor(sm[r], off);
    float inv[4];
#pragma unroll
    for (int r = 0; r < 4; ++r) inv[r] = 1.f / sm[r];
    // ---- PV in 3 col-chunks of 128 (Ps rows wave-private; no barriers)
    f32x4 pacc[4];
#pragma unroll
    for (int ni = 0; ni < 4; ++ni) pacc[ni] = (f32x4){0.f, 0.f, 0.f, 0.f};
#pragma unroll
    for (int ch = 0; ch < 3; ++ch) {
#pragma unroll
      for (int nl = 0; nl < 8; ++nl) {
        int n = ch * 8 + nl;
#pragma unroll
        for (int r = 0; r < 4; ++r) {
          int prow = wave * 16 + quad * 4 + r;
          int g = ((nl << 1) + (l16 >> 3)) ^ ((quad * 4 + r) & 7);
          Ps[prow * PROW + (g << 3) + l8] = f2bfu(sc[n][r] * inv[r]);
        }
      }
      __builtin_amdgcn_s_setprio(1);
#pragma unroll
      for (int kk = 0; kk < 4; ++kk) {
        bf16x8 pa = *(const bf16x8*)&Ps[(wave * 16 + l16) * PROW +
                                        ((((kk << 2) + quad) ^ l8) << 3)];
#pragma unroll
        for (int ni = 0; ni < 4; ++ni) {
          bf16x8 vb = *(const bf16x8*)&VT[(ni * 16 + l16) * VROW +
                                          ((((ch << 4) + (kk << 2) + quad) ^ l8) << 3)];
          pacc[ni] = __builtin_amdgcn_mfma_f32_16x16x32_bf16(pa, vb, pacc[ni], 0, 0, 0);
        }
      }
      __builtin_amdgcn_s_setprio(0);
    }
#pragma unroll
    for (int ni = 0; ni < 4; ++ni)
#pragma unroll
      for (int r = 0; r < 4; ++r) {
        int t = rowb + quad * 4 + r;
        if (t < TOKENS)
          ctx[basec + (size_t)t * CDIM + ni * 16 + l16] = f2bfu(pacc[ni][r]);
      }
  }
}

// ------------------------------------------------- launch
extern "C" void kernel_launch(void* const* d_in, const int* in_sizes, int n_in,
                              void* d_out, int out_size, void* d_ws, size_t ws_size,
                              hipStream_t stream) {
  const float* x     = (const float*)d_in[0];
  const float* ln1_s = (const float*)d_in[1];
  const float* ln1_b = (const float*)d_in[2];
  const float* Wq    = (const float*)d_in[3];
  const float* bq    = (const float*)d_in[4];
  const float* Wk    = (const float*)d_in[5];
  const float* bk    = (const float*)d_in[6];
  const float* Wv    = (const float*)d_in[7];
  const float* bv    = (const float*)d_in[8];
  const float* Wo    = (const float*)d_in[9];
  const float* bo    = (const float*)d_in[10];
  const float* relb  = (const float*)d_in[11];
  const float* ln2_s = (const float*)d_in[12];
  const float* ln2_b = (const float*)d_in[13];
  const float* W1    = (const float*)d_in[14];
  const float* b1    = (const float*)d_in[15];
  const float* W2    = (const float*)d_in[16];
  const float* b2    = (const float*)d_in[17];
  float* out = (float*)d_out;

  // ws layout (~385 MB): bf16 weights 6.3 MB | bqkv 6 KB | y 94.6 MB |
  // x1b 94.6 MB | qkv half-batch 142 MB + ctx 47.3 MB (overlaid by MLP hidden)
  char* ws = (char*)d_ws;
  unsigned short* WqT = (unsigned short*)ws;
  unsigned short* WkT = WqT + 512 * 512;
  unsigned short* WvT = WkT + 512 * 512;  // WqT|WkT|WvT contiguous = [1536][512]
  unsigned short* WoT = WvT + 512 * 512;
  unsigned short* W1T = WoT + 512 * 512;
  unsigned short* W2T = W1T + 512 * 2048;
  float* bqkv = (float*)(W2T + 2048 * 512);
  unsigned short* yb  = (unsigned short*)(bqkv + 1536);  // NTOK*512 bf16
  unsigned short* x1b = yb + (size_t)NTOK * CDIM;        // NTOK*512 bf16
  unsigned short* qkvb = x1b + (size_t)NTOK * CDIM;      // HTOK*1536 bf16
  unsigned short* ctxb = qkvb + (size_t)HTOK * QKVSTR;   // HTOK*512 bf16
  unsigned short* hdn  = qkvb;  // HTOK*2048 bf16, overlays qkv+ctx

  dim3 blk(256);
  transpose_conv<<<dim3(16, 16), blk, 0, stream>>>(Wq, WqT, 512, 512);
  transpose_conv<<<dim3(16, 16), blk, 0, stream>>>(Wk, WkT, 512, 512);
  transpose_conv<<<dim3(16, 16), blk, 0, stream>>>(Wv, WvT, 512, 512);
  transpose_conv<<<dim3(16, 16), blk, 0, stream>>>(Wo, WoT, 512, 512);
  transpose_conv<<<dim3(64, 16), blk, 0, stream>>>(W1, W1T, 512, 2048);
  transpose_conv<<<dim3(16, 64), blk, 0, stream>>>(W2, W2T, 2048, 512);
  concat_bias<<<dim3(6), blk, 0, stream>>>(bq, bk, bv, bqkv);

  ln_f32<<<NTOK / 4, blk, 0, stream>>>(x, ln1_s, ln1_b, yb);

  for (int c = 0; c < 2; ++c) {
    size_t off = (size_t)c * HTOK;
    const unsigned short* yc = yb + off * CDIM;
    gemm_bt<0><<<dim3(361 * 12), blk, 0, stream>>>(yc, WqT, bqkv, nullptr, nullptr,
                                                   qkvb, HTOK, 1536, 512, 12);
    attn_mfma<<<dim3((BATCH / 2) * NHEAD), dim3(512), 0, stream>>>(qkvb, relb, ctxb);
    gemm_bt<2><<<dim3(361 * 4), blk, 0, stream>>>(ctxb, WoT, bo, x + off * CDIM, nullptr,
                                                  x1b + off * CDIM, HTOK, 512, 512, 4);
  }

  ln_bf16<<<NTOK / 4, blk, 0, stream>>>(x1b, ln2_s, ln2_b, yb);

  for (int c = 0; c < 2; ++c) {
    size_t off = (size_t)c * HTOK;
    gemm_bt<1><<<dim3(361 * 16), blk, 0, stream>>>(yb + off * CDIM, W1T, b1, nullptr, nullptr,
                                                   hdn, HTOK, 2048, 512, 16);
    gemm_bt<3><<<dim3(361 * 4), blk, 0, stream>>>(hdn, W2T, b2, nullptr, x1b + off * CDIM,
                                                  out + off * CDIM, HTOK, 512, 2048, 4);
  }
}